// Round 1
// baseline (1004.139 us; speedup 1.0000x reference)
//
#include <hip/hip_runtime.h>

#define M_PIF 3.14159265358979323846f

constexpr int NP   = 8;     // point-group size
constexpr int NC   = 256;   // lattice cells (16x16)
constexpr int LAT  = 16;    // lattice side
constexpr int NS   = 2048;  // n_symm
constexpr int F    = 64;    // out features
constexpr int IF_  = 64;    // in features
constexpr int B    = 64;    // batch
constexpr int NTOT = 512;   // F * NP  (GEMM N)

// ---------------------------------------------------------------------------
// FFT of activations: xg[b,i,a,sy,sx] = x[b,i,(sy*16+sx)*8+a]
// -> xf[c][b][k] complex, c = ky*16+kx, k = il*8+a (chunk-local)
// Block: 256 threads = 16 FFTs (16 threads each). Block covers (b, il-pair).
// ---------------------------------------------------------------------------
__global__ __launch_bounds__(256) void fft_x_kernel(
    const float* __restrict__ x, float* __restrict__ xf_re, float* __restrict__ xf_im,
    int i0, int CI)
{
    __shared__ float ltwr[16], ltwi[16];
    __shared__ float t_re[16][273];
    __shared__ float t_im[16][273];
    const int tid = threadIdx.x;
    if (tid < 16) {
        float s, c; sincosf(-2.f * M_PIF * (float)tid / 16.f, &s, &c);
        ltwr[tid] = c; ltwi[tid] = s;
    }
    __syncthreads();
    float twr[16], twi[16];
#pragma unroll
    for (int j = 0; j < 16; ++j) { twr[j] = ltwr[j]; twi[j] = ltwi[j]; }

    const int g = tid >> 4;          // FFT id within block
    const int l = tid & 15;          // lane within FFT
    const int K = CI * 8;
    const int nip = CI >> 1;
    const int ip = blockIdx.x % nip;
    const int b  = blockIdx.x / nip;
    const int il = ip * 2 + (g >> 3);
    const int a  = g & 7;
    const int i  = i0 + il;

    // pass 1: row sy = l, real-input DFT over sx
    const float* xrow = x + ((size_t)b * IF_ + i) * NS;
    float v[16];
#pragma unroll
    for (int sx = 0; sx < 16; ++sx) v[sx] = xrow[(l * 16 + sx) * 8 + a];
#pragma unroll
    for (int k = 0; k < 16; ++k) {
        float sr = 0.f, si = 0.f;
#pragma unroll
        for (int n = 0; n < 16; ++n) {
            const int j = (k * n) & 15;
            sr = fmaf(v[n], twr[j], sr);
            si = fmaf(v[n], twi[j], si);
        }
        t_re[g][k * 17 + l] = sr;
        t_im[g][k * 17 + l] = si;
    }
    __syncthreads();

    // pass 2: column kx = l, complex DFT over sy
    float Tr[16], Ti[16];
#pragma unroll
    for (int n = 0; n < 16; ++n) { Tr[n] = t_re[g][l * 17 + n]; Ti[n] = t_im[g][l * 17 + n]; }
    float Xr[16], Xi[16];
#pragma unroll
    for (int k = 0; k < 16; ++k) {
        float sr = 0.f, si = 0.f;
#pragma unroll
        for (int n = 0; n < 16; ++n) {
            const int j = (k * n) & 15;
            sr = fmaf(Tr[n], twr[j], sr);
            sr = fmaf(-Ti[n], twi[j], sr);
            si = fmaf(Tr[n], twi[j], si);
            si = fmaf(Ti[n], twr[j], si);
        }
        Xr[k] = sr; Xi[k] = si;
    }
    __syncthreads();
#pragma unroll
    for (int k = 0; k < 16; ++k) { t_re[g][k * 16 + l] = Xr[k]; t_im[g][k * 16 + l] = Xi[k]; }
    __syncthreads();

    // cooperative coalesced store: xf[c][b][k0b + g2]
    const int k0b = ip * 16;
    for (int t = tid; t < 16 * 256; t += 256) {
        const int g2 = t & 15, c = t >> 4;
        const size_t addr = ((size_t)c * B + b) * K + k0b + g2;
        xf_re[addr] = t_re[g2][c];
        xf_im[addr] = t_im[g2][c];
    }
}

// ---------------------------------------------------------------------------
// Gather + FFT of kernel: kg[f,i,a,bq,sy,sx] = kernel[f,i, pt[a,(sy*16+sx)*8+bq]]
// -> kf[c][k][n] complex, k = il*8+a, n = f*8+bq
// Block: 256 threads = 16 FFTs; block covers fixed (il, a, f-pair), g=(fl, bq).
// ---------------------------------------------------------------------------
__global__ __launch_bounds__(256) void fft_k_kernel(
    const float* __restrict__ kern, const int* __restrict__ pt,
    float* __restrict__ kf_re, float* __restrict__ kf_im,
    int i0, int CI)
{
    __shared__ float krow[2][2048];
    __shared__ int   ptab[2048];
    __shared__ float ltwr[16], ltwi[16];
    __shared__ float t_re[16][273];
    __shared__ float t_im[16][273];
    const int tid = threadIdx.x;
    const int fp = blockIdx.x & 31;
    const int a  = (blockIdx.x >> 5) & 7;
    const int il = blockIdx.x >> 8;
    const int i  = i0 + il;

    if (tid < 16) {
        float s, c; sincosf(-2.f * M_PIF * (float)tid / 16.f, &s, &c);
        ltwr[tid] = c; ltwi[tid] = s;
    }
    for (int j = tid; j < 4096; j += 256) {
        const int fl = j >> 11, s = j & 2047;
        krow[fl][s] = kern[((size_t)(fp * 2 + fl) * IF_ + i) * NS + s];
    }
    for (int j = tid; j < 2048; j += 256) ptab[j] = pt[a * NS + j];
    __syncthreads();

    float twr[16], twi[16];
#pragma unroll
    for (int j = 0; j < 16; ++j) { twr[j] = ltwr[j]; twi[j] = ltwi[j]; }

    const int g  = tid >> 4;
    const int l  = tid & 15;
    const int fl = g >> 3;
    const int bq = g & 7;

    // pass 1: row sy = l (real input, gathered)
    float v[16];
#pragma unroll
    for (int sx = 0; sx < 16; ++sx) v[sx] = krow[fl][ptab[(l * 16 + sx) * 8 + bq]];
#pragma unroll
    for (int k = 0; k < 16; ++k) {
        float sr = 0.f, si = 0.f;
#pragma unroll
        for (int n = 0; n < 16; ++n) {
            const int j = (k * n) & 15;
            sr = fmaf(v[n], twr[j], sr);
            si = fmaf(v[n], twi[j], si);
        }
        t_re[g][k * 17 + l] = sr;
        t_im[g][k * 17 + l] = si;
    }
    __syncthreads();

    // pass 2: column kx = l, complex DFT over sy
    float Tr[16], Ti[16];
#pragma unroll
    for (int n = 0; n < 16; ++n) { Tr[n] = t_re[g][l * 17 + n]; Ti[n] = t_im[g][l * 17 + n]; }
    float Xr[16], Xi[16];
#pragma unroll
    for (int k = 0; k < 16; ++k) {
        float sr = 0.f, si = 0.f;
#pragma unroll
        for (int n = 0; n < 16; ++n) {
            const int j = (k * n) & 15;
            sr = fmaf(Tr[n], twr[j], sr);
            sr = fmaf(-Ti[n], twi[j], sr);
            si = fmaf(Tr[n], twi[j], si);
            si = fmaf(Ti[n], twr[j], si);
        }
        Xr[k] = sr; Xi[k] = si;
    }
    __syncthreads();
#pragma unroll
    for (int k = 0; k < 16; ++k) { t_re[g][k * 16 + l] = Xr[k]; t_im[g][k * 16 + l] = Xi[k]; }
    __syncthreads();

    // cooperative coalesced store: kf[(c*K + kl)*512 + n0 + g2]
    const int K  = CI * 8;
    const int kl = il * 8 + a;
    const int n0 = fp * 16;
    for (int t = tid; t < 4096; t += 256) {
        const int g2 = t & 15, c = t >> 4;
        const size_t addr = ((size_t)c * K + kl) * NTOT + n0 + g2;
        kf_re[addr] = t_re[g2][c];
        kf_im[addr] = t_im[g2][c];
    }
}

// ---------------------------------------------------------------------------
// Per-frequency complex GEMM: yf[c][b][n] (+)= sum_k xf[c][b][k] * kf[c][k][n]
// Block: 256 threads, C-tile 64x128 complex, 4x8 accum per thread.
// ---------------------------------------------------------------------------
__global__ __launch_bounds__(256) void gemm_kernel(
    const float* __restrict__ xf_re, const float* __restrict__ xf_im,
    const float* __restrict__ kf_re, const float* __restrict__ kf_im,
    float* __restrict__ yf_re, float* __restrict__ yf_im,
    int K, int accumulate)
{
    __shared__ float As_re[16][68], As_im[16][68];
    __shared__ float Bs_re[16][128], Bs_im[16][128];
    const int tid = threadIdx.x;
    const int c   = blockIdx.y;
    const int n0  = blockIdx.x * 128;
    const int ty  = tid >> 4, tx = tid & 15;
    const int ma  = tid >> 2, kq = tid & 3;
    const int kb  = tid >> 4, seg = tid & 15;

    float cre[4][8] = {}, cim[4][8] = {};
    const size_t abase = (size_t)c * B * K;
    const size_t bbase = (size_t)c * K * NTOT;

    for (int k0 = 0; k0 < K; k0 += 16) {
        const float4 ar  = *(const float4*)(xf_re + abase + (size_t)ma * K + k0 + kq * 4);
        const float4 ai  = *(const float4*)(xf_im + abase + (size_t)ma * K + k0 + kq * 4);
        const size_t brow = bbase + (size_t)(k0 + kb) * NTOT + n0 + seg * 8;
        const float4 br0 = *(const float4*)(kf_re + brow);
        const float4 br1 = *(const float4*)(kf_re + brow + 4);
        const float4 bi0 = *(const float4*)(kf_im + brow);
        const float4 bi1 = *(const float4*)(kf_im + brow + 4);
        __syncthreads();
        As_re[kq * 4 + 0][ma] = ar.x; As_re[kq * 4 + 1][ma] = ar.y;
        As_re[kq * 4 + 2][ma] = ar.z; As_re[kq * 4 + 3][ma] = ar.w;
        As_im[kq * 4 + 0][ma] = ai.x; As_im[kq * 4 + 1][ma] = ai.y;
        As_im[kq * 4 + 2][ma] = ai.z; As_im[kq * 4 + 3][ma] = ai.w;
        *(float4*)&Bs_re[kb][seg * 8]     = br0;
        *(float4*)&Bs_re[kb][seg * 8 + 4] = br1;
        *(float4*)&Bs_im[kb][seg * 8]     = bi0;
        *(float4*)&Bs_im[kb][seg * 8 + 4] = bi1;
        __syncthreads();
#pragma unroll
        for (int kk = 0; kk < 16; ++kk) {
            float arr[4], aii[4], brr[8], bii[8];
#pragma unroll
            for (int m = 0; m < 4; ++m) { arr[m] = As_re[kk][ty * 4 + m]; aii[m] = As_im[kk][ty * 4 + m]; }
#pragma unroll
            for (int n = 0; n < 8; ++n) { brr[n] = Bs_re[kk][tx * 8 + n]; bii[n] = Bs_im[kk][tx * 8 + n]; }
#pragma unroll
            for (int m = 0; m < 4; ++m)
#pragma unroll
                for (int n = 0; n < 8; ++n) {
                    cre[m][n] = fmaf(arr[m], brr[n], cre[m][n]);
                    cre[m][n] = fmaf(-aii[m], bii[n], cre[m][n]);
                    cim[m][n] = fmaf(arr[m], bii[n], cim[m][n]);
                    cim[m][n] = fmaf(aii[m], brr[n], cim[m][n]);
                }
        }
    }

    const size_t ybase = (size_t)c * B * NTOT;
#pragma unroll
    for (int m = 0; m < 4; ++m) {
        const size_t row = ybase + (size_t)(ty * 4 + m) * NTOT + n0 + tx * 8;
        if (accumulate) {
#pragma unroll
            for (int n = 0; n < 8; ++n) { cre[m][n] += yf_re[row + n]; cim[m][n] += yf_im[row + n]; }
        }
        *(float4*)(yf_re + row)     = make_float4(cre[m][0], cre[m][1], cre[m][2], cre[m][3]);
        *(float4*)(yf_re + row + 4) = make_float4(cre[m][4], cre[m][5], cre[m][6], cre[m][7]);
        *(float4*)(yf_im + row)     = make_float4(cim[m][0], cim[m][1], cim[m][2], cim[m][3]);
        *(float4*)(yf_im + row + 4) = make_float4(cim[m][4], cim[m][5], cim[m][6], cim[m][7]);
    }
}

// ---------------------------------------------------------------------------
// Inverse FFT + bias: out[b,f,s*8+p2] = real(ifft2(yf[.,b,f*8+p2]))[s] + bias[f]
// Block: 256 threads = 16 iFFTs; block covers (b, 16 consecutive n).
// ---------------------------------------------------------------------------
__global__ __launch_bounds__(256) void ifft_y_kernel(
    const float* __restrict__ yf_re, const float* __restrict__ yf_im,
    const float* __restrict__ bias, float* __restrict__ out)
{
    __shared__ float ltwr[16], ltwi[16];
    __shared__ float t_re[16][273];
    __shared__ float t_im[16][273];
    const int tid = threadIdx.x;
    const int b  = blockIdx.x >> 5;
    const int nt = blockIdx.x & 31;
    const int n0 = nt * 16;

    if (tid < 16) {
        float s, c; sincosf(2.f * M_PIF * (float)tid / 16.f, &s, &c);
        ltwr[tid] = c; ltwi[tid] = s;
    }
    // cooperative staged load: t[g][c] <- yf[c][b][n0+g]
    for (int t = tid; t < 4096; t += 256) {
        const int g2 = t & 15, c = t >> 4;
        const size_t addr = ((size_t)c * B + b) * NTOT + n0 + g2;
        t_re[g2][c] = yf_re[addr];
        t_im[g2][c] = yf_im[addr];
    }
    __syncthreads();
    float twr[16], twi[16];
#pragma unroll
    for (int j = 0; j < 16; ++j) { twr[j] = ltwr[j]; twi[j] = ltwi[j]; }

    const int g = tid >> 4;
    const int l = tid & 15;

    // pass 1: row ky = l, complex inverse DFT over kx
    float vr[16], vi[16];
#pragma unroll
    for (int kx = 0; kx < 16; ++kx) { vr[kx] = t_re[g][l * 16 + kx]; vi[kx] = t_im[g][l * 16 + kx]; }
    float Ar[16], Ai[16];
#pragma unroll
    for (int sx = 0; sx < 16; ++sx) {
        float sr = 0.f, si = 0.f;
#pragma unroll
        for (int n = 0; n < 16; ++n) {
            const int j = (sx * n) & 15;
            sr = fmaf(vr[n], twr[j], sr);
            sr = fmaf(-vi[n], twi[j], sr);
            si = fmaf(vr[n], twi[j], si);
            si = fmaf(vi[n], twr[j], si);
        }
        Ar[sx] = sr; Ai[sx] = si;
    }
    __syncthreads();
#pragma unroll
    for (int sx = 0; sx < 16; ++sx) { t_re[g][sx * 17 + l] = Ar[sx]; t_im[g][sx * 17 + l] = Ai[sx]; }
    __syncthreads();

    // pass 2: column sx = l, inverse DFT over ky, real part only
    float Ur[16], Ui[16];
#pragma unroll
    for (int n = 0; n < 16; ++n) { Ur[n] = t_re[g][l * 17 + n]; Ui[n] = t_im[g][l * 17 + n]; }
    float R[16];
#pragma unroll
    for (int sy = 0; sy < 16; ++sy) {
        float sr = 0.f;
#pragma unroll
        for (int n = 0; n < 16; ++n) {
            const int j = (sy * n) & 15;
            sr = fmaf(Ur[n], twr[j], sr);
            sr = fmaf(-Ui[n], twi[j], sr);
        }
        R[sy] = sr;
    }
    __syncthreads();
#pragma unroll
    for (int sy = 0; sy < 16; ++sy) t_re[g][sy * 16 + l] = R[sy];
    __syncthreads();

    // cooperative write: out[b, f0+fl, s*8 + q] = t[fl*8+q][s]/256 + bias
    const int f0 = nt * 2;
    for (int t = tid; t < 4096; t += 256) {
        const int q = t & 7, fl = (t >> 3) & 1, s = t >> 4;
        const int g2 = fl * 8 + q;
        const float val = t_re[g2][s] * (1.f / 256.f) + bias[f0 + fl];
        out[((size_t)b * F + f0 + fl) * NS + s * 8 + q] = val;
    }
}

// ---------------------------------------------------------------------------
extern "C" void kernel_launch(void* const* d_in, const int* in_sizes, int n_in,
                              void* d_out, int out_size, void* d_ws, size_t ws_size,
                              hipStream_t stream)
{
    const float* x    = (const float*)d_in[0];
    const float* kern = (const float*)d_in[1];
    const float* bias = (const float*)d_in[2];
    const int*   pt   = (const int*)d_in[3];
    float* out = (float*)d_out;

    // pick largest K-chunk (in-feature chunk CI) that fits workspace
    int CI = 2;
    const int cands[6] = {64, 32, 16, 8, 4, 2};
    for (int t = 0; t < 6; ++t) {
        const int cand = cands[t];
        const size_t need = (size_t)4 * ((size_t)2 * NC * B * cand * 8 +
                                         (size_t)2 * NC * cand * 8 * NTOT +
                                         (size_t)2 * NC * B * NTOT);
        if (need <= ws_size) { CI = cand; break; }
    }
    const int K = CI * 8;

    float* p = (float*)d_ws;
    float* xf_re = p; p += (size_t)NC * B * K;
    float* xf_im = p; p += (size_t)NC * B * K;
    float* kf_re = p; p += (size_t)NC * K * NTOT;
    float* kf_im = p; p += (size_t)NC * K * NTOT;
    float* yf_re = p; p += (size_t)NC * B * NTOT;
    float* yf_im = p;

    const int nchunks = IF_ / CI;
    for (int ch = 0; ch < nchunks; ++ch) {
        const int i0 = ch * CI;
        fft_x_kernel<<<B * (CI / 2), 256, 0, stream>>>(x, xf_re, xf_im, i0, CI);
        fft_k_kernel<<<CI * 8 * 32, 256, 0, stream>>>(kern, pt, kf_re, kf_im, i0, CI);
        gemm_kernel<<<dim3(4, NC), 256, 0, stream>>>(xf_re, xf_im, kf_re, kf_im,
                                                     yf_re, yf_im, K, ch > 0);
    }
    ifft_y_kernel<<<B * 32, 256, 0, stream>>>(yf_re, yf_im, bias, out);
}

// Round 2
// 573.225 us; speedup vs baseline: 1.7517x; 1.7517x over previous
//
#include <hip/hip_runtime.h>

#define M_PIF 3.14159265358979323846f

typedef __attribute__((ext_vector_type(8))) short bf16x8;
typedef __attribute__((ext_vector_type(16))) float f32x16;
typedef unsigned short ushort_t;

constexpr int NS  = 2048;  // n_symm
constexpr int F   = 64;    // out features
constexpr int IFT = 64;    // in features
constexpr int B   = 64;    // batch
constexpr int NCS = 144;   // stored half-spectrum cells: kx in 0..8, ky in 0..15; cs = kx*16+ky

__device__ inline ushort_t f2bf(float x) {
    unsigned u = __float_as_uint(x);
    unsigned r = u + 0x7FFFu + ((u >> 16) & 1u);
    return (ushort_t)(r >> 16);
}
__device__ inline float bf2f(ushort_t h) { return __uint_as_float(((unsigned)h) << 16); }

__device__ inline bf16x8 bneg(bf16x8 v) {
    union { bf16x8 b; unsigned u[4]; } x; x.b = v;
    x.u[0] ^= 0x80008000u; x.u[1] ^= 0x80008000u;
    x.u[2] ^= 0x80008000u; x.u[3] ^= 0x80008000u;
    return x.b;
}

// ---------------------------------------------------------------------------
// pt2[a][bq][s] = pt[a][s*8+bq]  (gather table pre-permuted for coalesced reads)
// ---------------------------------------------------------------------------
__global__ __launch_bounds__(256) void permute_pt_kernel(
    const int* __restrict__ pt, int* __restrict__ pt2)
{
    const int t = blockIdx.x * 256 + threadIdx.x;   // 16384
    const int a = t >> 11, r = t & 2047;
    const int bq = r >> 8, s = r & 255;
    pt2[t] = pt[a * NS + s * 8 + bq];
}

// ---------------------------------------------------------------------------
// fft_x: x[b,i,s*8+a] -> half-spectrum A-fragments (bf16 hi/lo, re/im)
// xf[(((cs*KB+kb)*2+mt)*4+v)*512 + lane*8 + j]
//   A[m=lane&31][k16=(lane>>5)*8+j], m=b (mt=b>>5), k_local=il*8+a, v in {rh,rl,ih,il}
// Block: (bp, il): 16 FFTs = a(0..7) x bloc(0..1), b = bp*2+bloc.
// ---------------------------------------------------------------------------
__global__ __launch_bounds__(256) void fft_x_kernel(
    const float* __restrict__ x, ushort_t* __restrict__ xf, int i0, int KB)
{
    __shared__ float tw_r[16], tw_i[16];
    __shared__ float t_re[16][160], t_im[16][160];
    __shared__ __align__(16) ushort_t stg[NCS][2][8][4];  // [cs][bloc][a][v]
    const int tid = threadIdx.x;
    const int bp = blockIdx.x;   // 0..31
    const int il = blockIdx.y;   // 0..CI-1
    if (tid < 16) { float s, c; sincosf(-2.f * M_PIF * tid / 16.f, &s, &c); tw_r[tid] = c; tw_i[tid] = s; }
    __syncthreads();
    float twr[16], twi[16];
#pragma unroll
    for (int j = 0; j < 16; ++j) { twr[j] = tw_r[j]; twi[j] = tw_i[j]; }

    const int g = tid >> 4, l = tid & 15;
    const int bloc = g & 1, a = g >> 1;
    const int b = bp * 2 + bloc;
    const int i = i0 + il;

    // pass 1: row sy=l, real DFT over sx, only kx 0..8
    const float* xr = x + ((size_t)b * IFT + i) * NS;
    float v[16];
#pragma unroll
    for (int sx = 0; sx < 16; ++sx) v[sx] = xr[(l * 16 + sx) * 8 + a];
#pragma unroll
    for (int kx = 0; kx < 9; ++kx) {
        float sr = 0.f, si = 0.f;
#pragma unroll
        for (int n = 0; n < 16; ++n) {
            const int j = (kx * n) & 15;
            sr = fmaf(v[n], twr[j], sr);
            si = fmaf(v[n], twi[j], si);
        }
        t_re[g][kx * 17 + l] = sr;
        t_im[g][kx * 17 + l] = si;
    }
    __syncthreads();

    // pass 2: column kx=l (l<=8), complex DFT over sy, all ky
    if (l < 9) {
        float Tr[16], Ti[16];
#pragma unroll
        for (int n = 0; n < 16; ++n) { Tr[n] = t_re[g][l * 17 + n]; Ti[n] = t_im[g][l * 17 + n]; }
#pragma unroll
        for (int ky = 0; ky < 16; ++ky) {
            float sr = 0.f, si = 0.f;
#pragma unroll
            for (int n = 0; n < 16; ++n) {
                const int j = (ky * n) & 15;
                sr = fmaf(Tr[n], twr[j], sr); sr = fmaf(-Ti[n], twi[j], sr);
                si = fmaf(Tr[n], twi[j], si); si = fmaf(Ti[n], twr[j], si);
            }
            const int cs = l * 16 + ky;
            const ushort_t rh = f2bf(sr); const ushort_t rl = f2bf(sr - bf2f(rh));
            const ushort_t ih = f2bf(si); const ushort_t ilo = f2bf(si - bf2f(ih));
            const unsigned w0 = (unsigned)rh | ((unsigned)rl << 16);
            const unsigned w1 = (unsigned)ih | ((unsigned)ilo << 16);
            *(uint2*)&stg[cs][bloc][a][0] = make_uint2(w0, w1);
        }
    }
    __syncthreads();

    // cooperative fragment write (16B chunks)
    const int kb = il >> 1, mt = bp >> 4;
    const int lb = (il & 1) * 32 + (bp & 15) * 2;
    for (int t = tid; t < NCS * 4 * 2; t += 256) {
        const int cs = t >> 3, v4 = (t >> 1) & 3, h = t & 1;
        union { ushort_t s[8]; uint4 u; } tmp;
#pragma unroll
        for (int j = 0; j < 8; ++j) tmp.s[j] = stg[cs][h][j][v4];
        const size_t off = ((((size_t)cs * KB + kb) * 2 + mt) * 4 + v4) * 512 + (size_t)(lb + h) * 8;
        *(uint4*)(xf + off) = tmp.u;
    }
}

// ---------------------------------------------------------------------------
// fft_k: gather kernel[f,i,pt[a][s*8+bq]] -> half-spectrum B-fragments
// kf[(((cs*KB+kb)*16+nt)*4+v)*512 + lane*8 + j]
//   B[k16=(lane>>5)*8+j][n=(lane&31)+nt*32], n=f*8+bq, k_local=il*8+a
// Block: (fg*4+fr, bqp, il): per f-round 16 FFTs = a(0..7) x bql(0..1).
// ---------------------------------------------------------------------------
__global__ __launch_bounds__(256) void fft_k_kernel(
    const float* __restrict__ kern, const int* __restrict__ pt2,
    ushort_t* __restrict__ kf, int i0, int KB)
{
    __shared__ float tw_r[16], tw_i[16];
    __shared__ float krow[2048];
    __shared__ float t_re[16][160], t_im[16][160];
    __shared__ __align__(16) ushort_t stg[NCS][2][8][4];  // [cs][bql][a][v]
    const int tid = threadIdx.x;
    const int bx = blockIdx.x;   // 0..63: fg(4 f's) x bqp
    const int il = blockIdx.y;
    const int fg = bx >> 2, bqp = bx & 3;
    const int i = i0 + il;
    if (tid < 16) { float s, c; sincosf(-2.f * M_PIF * tid / 16.f, &s, &c); tw_r[tid] = c; tw_i[tid] = s; }
    __syncthreads();
    float twr[16], twi[16];
#pragma unroll
    for (int j = 0; j < 16; ++j) { twr[j] = tw_r[j]; twi[j] = tw_i[j]; }

    const int g = tid >> 4, l = tid & 15;
    const int bql = g & 1, a = g >> 1;
    const int bq = bqp * 2 + bql;

    // gather indices (constant across f-rounds), coalesced 64B/thread
    int idx[16];
    const int4* pp = (const int4*)(pt2 + ((a * 8 + bq) * 256 + l * 16));
#pragma unroll
    for (int q = 0; q < 4; ++q) {
        const int4 t4 = pp[q];
        idx[q * 4] = t4.x; idx[q * 4 + 1] = t4.y; idx[q * 4 + 2] = t4.z; idx[q * 4 + 3] = t4.w;
    }

    const int kb = il >> 1;
    for (int fr = 0; fr < 4; ++fr) {
        const int f = fg * 4 + fr;
        __syncthreads();   // protect krow/stg reuse across rounds
        {
            const float4* src = (const float4*)(kern + ((size_t)f * IFT + i) * NS);
            for (int u = tid; u < 512; u += 256) ((float4*)krow)[u] = src[u];
        }
        __syncthreads();

        // pass 1: row sy=l, gathered real DFT over sx, kx 0..8
        float v[16];
#pragma unroll
        for (int sx = 0; sx < 16; ++sx) v[sx] = krow[idx[sx]];
#pragma unroll
        for (int kx = 0; kx < 9; ++kx) {
            float sr = 0.f, si = 0.f;
#pragma unroll
            for (int n = 0; n < 16; ++n) {
                const int j = (kx * n) & 15;
                sr = fmaf(v[n], twr[j], sr);
                si = fmaf(v[n], twi[j], si);
            }
            t_re[g][kx * 17 + l] = sr;
            t_im[g][kx * 17 + l] = si;
        }
        __syncthreads();

        // pass 2
        if (l < 9) {
            float Tr[16], Ti[16];
#pragma unroll
            for (int n = 0; n < 16; ++n) { Tr[n] = t_re[g][l * 17 + n]; Ti[n] = t_im[g][l * 17 + n]; }
#pragma unroll
            for (int ky = 0; ky < 16; ++ky) {
                float sr = 0.f, si = 0.f;
#pragma unroll
                for (int n = 0; n < 16; ++n) {
                    const int j = (ky * n) & 15;
                    sr = fmaf(Tr[n], twr[j], sr); sr = fmaf(-Ti[n], twi[j], sr);
                    si = fmaf(Tr[n], twi[j], si); si = fmaf(Ti[n], twr[j], si);
                }
                const int cs = l * 16 + ky;
                const ushort_t rh = f2bf(sr); const ushort_t rl = f2bf(sr - bf2f(rh));
                const ushort_t ih = f2bf(si); const ushort_t ilo = f2bf(si - bf2f(ih));
                const unsigned w0 = (unsigned)rh | ((unsigned)rl << 16);
                const unsigned w1 = (unsigned)ih | ((unsigned)ilo << 16);
                *(uint2*)&stg[cs][bql][a][0] = make_uint2(w0, w1);
            }
        }
        __syncthreads();

        // cooperative fragment write
        const int nt = f >> 2;
        const int lbase = (il & 1) * 32 + (f & 3) * 8 + bqp * 2;
        for (int t = tid; t < NCS * 4 * 2; t += 256) {
            const int cs = t >> 3, v4 = (t >> 1) & 3, h = t & 1;
            union { ushort_t s[8]; uint4 u; } tmp;
#pragma unroll
            for (int j = 0; j < 8; ++j) tmp.s[j] = stg[cs][h][j][v4];
            const size_t off = ((((size_t)cs * KB + kb) * 16 + nt) * 4 + v4) * 512 + (size_t)(lbase + h) * 8;
            *(uint4*)(kf + off) = tmp.u;
        }
    }
}

// ---------------------------------------------------------------------------
// MFMA complex GEMM, split-bf16 (hi/lo), no LDS.
// yf[c][b][n] (+)= sum_k xf[c][b][k] * kf[c][k][n]  for 144 half-spectrum cells.
// Block: 256 thr = 4 waves; wave = M64 x N32 (2 mt), 24 mfma_32x32x16 per k16.
// ---------------------------------------------------------------------------
#define MFMA(acc, A, Bv) acc = __builtin_amdgcn_mfma_f32_32x32x16_bf16(A, Bv, acc, 0, 0, 0)

__global__ __launch_bounds__(256) void gemm_kernel(
    const ushort_t* __restrict__ xf, const ushort_t* __restrict__ kf,
    float* __restrict__ yre, float* __restrict__ yim, int KB, int acc)
{
    const int cs = blockIdx.y, nb = blockIdx.x;
    const int w = threadIdx.x >> 6, lane = threadIdx.x & 63;
    const int nt = nb * 4 + w;

    f32x16 cre0, cim0, cre1, cim1;
#pragma unroll
    for (int q = 0; q < 16; ++q) { cre0[q] = 0.f; cim0[q] = 0.f; cre1[q] = 0.f; cim1[q] = 0.f; }

    const ushort_t* ab = xf + (size_t)cs * KB * 4096 + (size_t)lane * 8;
    const ushort_t* bb = kf + (size_t)cs * KB * 32768 + (size_t)nt * 2048 + (size_t)lane * 8;

    for (int kb = 0; kb < KB; ++kb) {
        const ushort_t* ap = ab + (size_t)kb * 4096;
        const ushort_t* bp = bb + (size_t)kb * 32768;
        const bf16x8 Brh = *(const bf16x8*)(bp);
        const bf16x8 Brl = *(const bf16x8*)(bp + 512);
        const bf16x8 Bih = *(const bf16x8*)(bp + 1024);
        const bf16x8 Bil = *(const bf16x8*)(bp + 1536);
        const bf16x8 Arh0 = *(const bf16x8*)(ap);
        const bf16x8 Arl0 = *(const bf16x8*)(ap + 512);
        const bf16x8 Aih0 = *(const bf16x8*)(ap + 1024);
        const bf16x8 Ail0 = *(const bf16x8*)(ap + 1536);
        const bf16x8 Arh1 = *(const bf16x8*)(ap + 2048);
        const bf16x8 Arl1 = *(const bf16x8*)(ap + 2560);
        const bf16x8 Aih1 = *(const bf16x8*)(ap + 3072);
        const bf16x8 Ail1 = *(const bf16x8*)(ap + 3584);
        const bf16x8 NAih0 = bneg(Aih0), NAil0 = bneg(Ail0);
        const bf16x8 NAih1 = bneg(Aih1), NAil1 = bneg(Ail1);

        MFMA(cre0, Arh0, Brh); MFMA(cre0, Arl0, Brh); MFMA(cre0, Arh0, Brl);
        MFMA(cre0, NAih0, Bih); MFMA(cre0, NAil0, Bih); MFMA(cre0, NAih0, Bil);
        MFMA(cim0, Arh0, Bih); MFMA(cim0, Arl0, Bih); MFMA(cim0, Arh0, Bil);
        MFMA(cim0, Aih0, Brh); MFMA(cim0, Ail0, Brh); MFMA(cim0, Aih0, Brl);
        MFMA(cre1, Arh1, Brh); MFMA(cre1, Arl1, Brh); MFMA(cre1, Arh1, Brl);
        MFMA(cre1, NAih1, Bih); MFMA(cre1, NAil1, Bih); MFMA(cre1, NAih1, Bil);
        MFMA(cim1, Arh1, Bih); MFMA(cim1, Arl1, Bih); MFMA(cim1, Arh1, Bil);
        MFMA(cim1, Aih1, Brh); MFMA(cim1, Ail1, Brh); MFMA(cim1, Aih1, Brl);
    }

    // epilogue: C/D layout col=lane&31, row=(reg&3)+8*(reg>>2)+4*(lane>>5)
    const int col = lane & 31, rhi = (lane >> 5) * 4;
    const int n = nb * 128 + w * 32 + col;
#pragma unroll
    for (int mt = 0; mt < 2; ++mt) {
        const f32x16 cr = mt ? cre1 : cre0;
        const f32x16 ci = mt ? cim1 : cim0;
#pragma unroll
        for (int reg = 0; reg < 16; ++reg) {
            const int row = (reg & 3) + 8 * (reg >> 2) + rhi;
            const size_t off = ((size_t)cs * B + mt * 32 + row) * 512 + n;
            float vr = cr[reg], vi = ci[reg];
            if (acc) { vr += yre[off]; vi += yim[off]; }
            yre[off] = vr; yim[off] = vi;
        }
    }
}

// ---------------------------------------------------------------------------
// ifft: mirror half-spectrum to full, 2D inverse DFT, +bias, real output.
// Block: (ng, b): 16 iFFTs over n = ng*16..+15  (covers out rows f0=ng*2, +1)
// ---------------------------------------------------------------------------
__global__ __launch_bounds__(256) void ifft_y_kernel(
    const float* __restrict__ yre, const float* __restrict__ yim,
    const float* __restrict__ bias, float* __restrict__ out)
{
    __shared__ float tw_r[16], tw_i[16];
    __shared__ float yr_s[NCS][17], yi_s[NCS][17];
    __shared__ float t_re[16][273], t_im[16][273];
    __shared__ float ost[2][256][8];
    const int tid = threadIdx.x;
    const int ng = blockIdx.x;   // 0..31
    const int b = blockIdx.y;
    const int n0 = ng * 16;
    if (tid < 16) { float s, c; sincosf(2.f * M_PIF * tid / 16.f, &s, &c); tw_r[tid] = c; tw_i[tid] = s; }
    for (int t = tid; t < NCS * 16; t += 256) {
        const int cs = t >> 4, nl = t & 15;
        const size_t off = ((size_t)cs * B + b) * 512 + n0 + nl;
        yr_s[cs][nl] = yre[off];
        yi_s[cs][nl] = yim[off];
    }
    __syncthreads();
    float twr[16], twi[16];
#pragma unroll
    for (int j = 0; j < 16; ++j) { twr[j] = tw_r[j]; twi[j] = tw_i[j]; }

    const int g = tid >> 4, l = tid & 15;

    // pass 1: row ky=l, reconstruct full kx spectrum via Hermitian mirror
    float Yr[16], Yi[16];
#pragma unroll
    for (int kx = 0; kx < 16; ++kx) {
        if (kx <= 8) {
            const int cs = kx * 16 + l;
            Yr[kx] = yr_s[cs][g]; Yi[kx] = yi_s[cs][g];
        } else {
            const int cs = (16 - kx) * 16 + ((16 - l) & 15);
            Yr[kx] = yr_s[cs][g]; Yi[kx] = -yi_s[cs][g];
        }
    }
#pragma unroll
    for (int sx = 0; sx < 16; ++sx) {
        float sr = 0.f, si = 0.f;
#pragma unroll
        for (int n = 0; n < 16; ++n) {
            const int j = (sx * n) & 15;
            sr = fmaf(Yr[n], twr[j], sr); sr = fmaf(-Yi[n], twi[j], sr);
            si = fmaf(Yr[n], twi[j], si); si = fmaf(Yi[n], twr[j], si);
        }
        t_re[g][sx * 17 + l] = sr;
        t_im[g][sx * 17 + l] = si;
    }
    __syncthreads();

    // pass 2: column sx=l, inverse DFT over ky, real part only
    float Tr[16], Ti[16];
#pragma unroll
    for (int n = 0; n < 16; ++n) { Tr[n] = t_re[g][l * 17 + n]; Ti[n] = t_im[g][l * 17 + n]; }
    const int fl = g >> 3, pq = g & 7;
#pragma unroll
    for (int sy = 0; sy < 16; ++sy) {
        float sr = 0.f;
#pragma unroll
        for (int n = 0; n < 16; ++n) {
            const int j = (sy * n) & 15;
            sr = fmaf(Tr[n], twr[j], sr); sr = fmaf(-Ti[n], twi[j], sr);
        }
        ost[fl][sy * 16 + l][pq] = sr * (1.f / 256.f);
    }
    __syncthreads();

    const int f0 = ng * 2;
    for (int t = tid; t < 4096; t += 256) {
        const int flv = t >> 11, e = t & 2047;
        out[((size_t)b * F + f0 + flv) * NS + e] = ost[flv][e >> 3][e & 7] + bias[f0 + flv];
    }
}

// ---------------------------------------------------------------------------
extern "C" void kernel_launch(void* const* d_in, const int* in_sizes, int n_in,
                              void* d_out, int out_size, void* d_ws, size_t ws_size,
                              hipStream_t stream)
{
    const float* x = (const float*)d_in[0];
    const float* kern = (const float*)d_in[1];
    const float* bias = (const float*)d_in[2];
    const int* pt = (const int*)d_in[3];
    float* out = (float*)d_out;

    // largest in-feature chunk CI that fits workspace
    int CI = 2;
    const int cands[6] = {64, 32, 16, 8, 4, 2};
    for (int t = 0; t < 6; ++t) {
        const int KBc = cands[t] / 2;
        const size_t need = 65536                         // pt2
                          + (size_t)NCS * KBc * 8192      // xf (bf16 frags)
                          + (size_t)NCS * KBc * 65536     // kf (bf16 frags)
                          + 2 * (size_t)NCS * B * 512 * 4; // yf re/im fp32
        if (need <= ws_size) { CI = cands[t]; break; }
    }
    const int KB = CI / 2;

    char* p = (char*)d_ws;
    int* pt2 = (int*)p;        p += 65536;
    ushort_t* xf = (ushort_t*)p; p += (size_t)NCS * KB * 8192;
    ushort_t* kf = (ushort_t*)p; p += (size_t)NCS * KB * 65536;
    float* yre = (float*)p;    p += (size_t)NCS * B * 512 * 4;
    float* yim = (float*)p;

    permute_pt_kernel<<<64, 256, 0, stream>>>(pt, pt2);

    const int nch = IFT / CI;
    for (int ch = 0; ch < nch; ++ch) {
        const int i0 = ch * CI;
        fft_x_kernel<<<dim3(32, CI), 256, 0, stream>>>(x, xf, i0, KB);
        fft_k_kernel<<<dim3(64, CI), 256, 0, stream>>>(kern, pt2, kf, i0, KB);
        gemm_kernel<<<dim3(4, NCS), 256, 0, stream>>>(xf, kf, yre, yim, KB, ch > 0);
    }
    ifft_y_kernel<<<dim3(32, B), 256, 0, stream>>>(yre, yim, bias, out);
}

// Round 3
// 364.927 us; speedup vs baseline: 2.7516x; 1.5708x over previous
//
#include <hip/hip_runtime.h>

#define M_PIF 3.14159265358979323846f

typedef __attribute__((ext_vector_type(8))) short bf16x8;
typedef __attribute__((ext_vector_type(16))) float f32x16;
typedef unsigned short ushort_t;

constexpr int NS  = 2048;  // n_symm
constexpr int F   = 64;    // out features
constexpr int IFT = 64;    // in features
constexpr int B   = 64;    // batch
constexpr int NCS = 144;   // half-spectrum cells: cs = ky*9 + kx, kx in 0..8, ky in 0..15

__device__ inline ushort_t f2bf(float x) {
    unsigned u = __float_as_uint(x);
    unsigned r = u + 0x7FFFu + ((u >> 16) & 1u);
    return (ushort_t)(r >> 16);
}
__device__ inline float bf2f(ushort_t h) { return __uint_as_float(((unsigned)h) << 16); }

__device__ inline bf16x8 bneg(bf16x8 v) {
    union { bf16x8 b; unsigned u[4]; } x; x.b = v;
    x.u[0] ^= 0x80008000u; x.u[1] ^= 0x80008000u;
    x.u[2] ^= 0x80008000u; x.u[3] ^= 0x80008000u;
    return x.b;
}

// ---------------------------------------------------------------------------
// pt2[a][bq][s] = pt[a][s*8+bq]
// ---------------------------------------------------------------------------
__global__ __launch_bounds__(256) void permute_pt_kernel(
    const int* __restrict__ pt, int* __restrict__ pt2)
{
    const int t = blockIdx.x * 256 + threadIdx.x;   // 16384
    const int a = t >> 11, r = t & 2047;
    const int bq = r >> 8, s = r & 255;
    pt2[t] = pt[a * NS + s * 8 + bq];
}

// ---------------------------------------------------------------------------
// fft_x: x[b,i,s*8+a] -> A-fragments (bf16 hi/lo, re/im: 4 planes)
// xf[(((cs*KB+kb)*2+mt)*4+v)*512 + lane*8 + j]
//   A[m=lane&31][k16=(lane>>5)*8+j], m=b (mt=b>>5), k_local=il*8+a
// ---------------------------------------------------------------------------
__global__ __launch_bounds__(256) void fft_x_kernel(
    const float* __restrict__ x, ushort_t* __restrict__ xf, int i0, int KB)
{
    __shared__ float tw_r[16], tw_i[16];
    __shared__ float t_re[16][168], t_im[16][168];   // 168 % 32 == 8 -> 2-way max
    __shared__ ushort_t stgx[NCS * 68];              // row 34 words; write stride 34 ~ bank-free
    const int tid = threadIdx.x;
    const int bp = blockIdx.x;   // 0..31
    const int il = blockIdx.y;   // 0..CI-1
    if (tid < 16) { float s, c; sincosf(-2.f * M_PIF * tid / 16.f, &s, &c); tw_r[tid] = c; tw_i[tid] = s; }
    __syncthreads();
    float twr[16], twi[16];
#pragma unroll
    for (int j = 0; j < 16; ++j) { twr[j] = tw_r[j]; twi[j] = tw_i[j]; }

    const int g = tid >> 4, l = tid & 15;
    const int bloc = g & 1, a = g >> 1;
    const int b = bp * 2 + bloc;
    const int i = i0 + il;

    // pass 1: row sy=l, real DFT over sx, kx 0..8
    const float* xr = x + ((size_t)b * IFT + i) * NS;
    float v[16];
#pragma unroll
    for (int sx = 0; sx < 16; ++sx) v[sx] = xr[(l * 16 + sx) * 8 + a];
#pragma unroll
    for (int kx = 0; kx < 9; ++kx) {
        float sr = 0.f, si = 0.f;
#pragma unroll
        for (int n = 0; n < 16; ++n) {
            const int j = (kx * n) & 15;
            sr = fmaf(v[n], twr[j], sr);
            si = fmaf(v[n], twi[j], si);
        }
        t_re[g][kx * 17 + l] = sr;
        t_im[g][kx * 17 + l] = si;
    }
    __syncthreads();

    // pass 2: column kx=l (l<9), complex DFT over sy
    if (l < 9) {
        float Tr[16], Ti[16];
#pragma unroll
        for (int n = 0; n < 16; ++n) { Tr[n] = t_re[g][l * 17 + n]; Ti[n] = t_im[g][l * 17 + n]; }
#pragma unroll
        for (int ky = 0; ky < 16; ++ky) {
            float sr = 0.f, si = 0.f;
#pragma unroll
            for (int n = 0; n < 16; ++n) {
                const int j = (ky * n) & 15;
                sr = fmaf(Tr[n], twr[j], sr); sr = fmaf(-Ti[n], twi[j], sr);
                si = fmaf(Tr[n], twi[j], si); si = fmaf(Ti[n], twr[j], si);
            }
            const int cs = ky * 9 + l;
            const ushort_t rh = f2bf(sr); const ushort_t rl = f2bf(sr - bf2f(rh));
            const ushort_t ih = f2bf(si); const ushort_t ilo = f2bf(si - bf2f(ih));
            const unsigned w0 = (unsigned)rh | ((unsigned)rl << 16);
            const unsigned w1 = (unsigned)ih | ((unsigned)ilo << 16);
            *(uint2*)&stgx[cs * 68 + bloc * 32 + a * 4] = make_uint2(w0, w1);
        }
    }
    __syncthreads();

    // fragment assembly: v planes {rh,rl,ih,il}
    const int kb = il >> 1, mt = bp >> 4;
    const int lb = (il & 1) * 32 + (bp & 15) * 2;
    for (int t = tid; t < NCS * 8; t += 256) {
        const int cs = t >> 3, v4 = (t >> 1) & 3, h = t & 1;
        union { ushort_t s[8]; uint4 u; } tmp;
        const int base = cs * 68 + h * 32 + (v4 >> 1) * 2 + (v4 & 1);
#pragma unroll
        for (int j = 0; j < 8; ++j) tmp.s[j] = stgx[base + j * 4];
        const size_t off = ((((size_t)cs * KB + kb) * 2 + mt) * 4 + v4) * 512 + (size_t)(lb + h) * 8;
        *(uint4*)(xf + off) = tmp.u;
    }
}

// ---------------------------------------------------------------------------
// fft_k: gather kernel[f,i,pt[a][s*8+bq]] -> B-fragments, bf16 (2 planes re,im)
// kf[(((cs*KB+kb)*16+nt)*2+v)*512 + lane*8 + j]
//   B[k16=(lane>>5)*8+j][n=(lane&31)+nt*32], n=f*8+bq, k_local=il*8+a
// ---------------------------------------------------------------------------
__global__ __launch_bounds__(256) void fft_k_kernel(
    const float* __restrict__ kern, const int* __restrict__ pt2,
    ushort_t* __restrict__ kf, int i0, int KB)
{
    __shared__ float tw_r[16], tw_i[16];
    __shared__ float krow[2048];
    __shared__ float t_re[16][168], t_im[16][168];
    __shared__ unsigned stgk[NCS * 18];              // row 18 words; write banks 18*kx distinct
    const int tid = threadIdx.x;
    const int bx = blockIdx.x;   // 0..63: fg(4 f's) x bqp
    const int il = blockIdx.y;
    const int fg = bx >> 2, bqp = bx & 3;
    const int i = i0 + il;
    if (tid < 16) { float s, c; sincosf(-2.f * M_PIF * tid / 16.f, &s, &c); tw_r[tid] = c; tw_i[tid] = s; }
    __syncthreads();
    float twr[16], twi[16];
#pragma unroll
    for (int j = 0; j < 16; ++j) { twr[j] = tw_r[j]; twi[j] = tw_i[j]; }

    const int g = tid >> 4, l = tid & 15;
    const int bql = g & 1, a = g >> 1;
    const int bq = bqp * 2 + bql;

    // gather indices (constant across f-rounds)
    int idx[16];
    const int4* pp = (const int4*)(pt2 + ((a * 8 + bq) * 256 + l * 16));
#pragma unroll
    for (int q = 0; q < 4; ++q) {
        const int4 t4 = pp[q];
        idx[q * 4] = t4.x; idx[q * 4 + 1] = t4.y; idx[q * 4 + 2] = t4.z; idx[q * 4 + 3] = t4.w;
    }

    const int kb = il >> 1;
    for (int fr = 0; fr < 4; ++fr) {
        const int f = fg * 4 + fr;
        __syncthreads();
        {
            const float4* src = (const float4*)(kern + ((size_t)f * IFT + i) * NS);
            for (int u = tid; u < 512; u += 256) ((float4*)krow)[u] = src[u];
        }
        __syncthreads();

        // pass 1: row sy=l, gathered real DFT over sx, kx 0..8
        float v[16];
#pragma unroll
        for (int sx = 0; sx < 16; ++sx) v[sx] = krow[idx[sx]];
#pragma unroll
        for (int kx = 0; kx < 9; ++kx) {
            float sr = 0.f, si = 0.f;
#pragma unroll
            for (int n = 0; n < 16; ++n) {
                const int j = (kx * n) & 15;
                sr = fmaf(v[n], twr[j], sr);
                si = fmaf(v[n], twi[j], si);
            }
            t_re[g][kx * 17 + l] = sr;
            t_im[g][kx * 17 + l] = si;
        }
        __syncthreads();

        // pass 2: column kx=l (l<9), complex DFT over sy; pack bf16 re/im
        if (l < 9) {
            float Tr[16], Ti[16];
#pragma unroll
            for (int n = 0; n < 16; ++n) { Tr[n] = t_re[g][l * 17 + n]; Ti[n] = t_im[g][l * 17 + n]; }
#pragma unroll
            for (int ky = 0; ky < 16; ++ky) {
                float sr = 0.f, si = 0.f;
#pragma unroll
                for (int n = 0; n < 16; ++n) {
                    const int j = (ky * n) & 15;
                    sr = fmaf(Tr[n], twr[j], sr); sr = fmaf(-Ti[n], twi[j], sr);
                    si = fmaf(Tr[n], twi[j], si); si = fmaf(Ti[n], twr[j], si);
                }
                const int cs = ky * 9 + l;
                stgk[cs * 18 + bql * 8 + a] = (unsigned)f2bf(sr) | ((unsigned)f2bf(si) << 16);
            }
        }
        __syncthreads();

        // fragment assembly: v planes {re, im}
        const int nt = f >> 2;
        const int lbase = (il & 1) * 32 + (f & 3) * 8 + bqp * 2;
        for (int t = tid; t < NCS * 2; t += 256) {
            const int cs = t >> 1, h = t & 1;
            const int base = cs * 18 + h * 8;
            unsigned w[8];
            *(uint2*)&w[0] = *(const uint2*)&stgk[base];
            *(uint2*)&w[2] = *(const uint2*)&stgk[base + 2];
            *(uint2*)&w[4] = *(const uint2*)&stgk[base + 4];
            *(uint2*)&w[6] = *(const uint2*)&stgk[base + 6];
            union { ushort_t s[8]; uint4 u; } lo, hi;
#pragma unroll
            for (int j = 0; j < 8; ++j) { lo.s[j] = (ushort_t)(w[j] & 0xffffu); hi.s[j] = (ushort_t)(w[j] >> 16); }
            const size_t off0 = ((((size_t)cs * KB + kb) * 16 + nt) * 2 + 0) * 512 + (size_t)(lbase + h) * 8;
            *(uint4*)(kf + off0) = lo.u;
            *(uint4*)(kf + off0 + 512) = hi.u;
        }
    }
}

// ---------------------------------------------------------------------------
// MFMA complex GEMM, A split-bf16 (hi/lo), B plain bf16, no LDS.
// Block: 256 thr = 4 waves; wave = M64 x N32; 16 mfma_32x32x16 per k16.
// ---------------------------------------------------------------------------
#define MFMA(acc, A, Bv) acc = __builtin_amdgcn_mfma_f32_32x32x16_bf16(A, Bv, acc, 0, 0, 0)
#define LDB(p) (*(const bf16x8*)(p))

__global__ __launch_bounds__(256) void gemm_kernel(
    const ushort_t* __restrict__ xf, const ushort_t* __restrict__ kf,
    float* __restrict__ yre, float* __restrict__ yim, int KB, int acc)
{
    const int cs = blockIdx.y, nb = blockIdx.x;
    const int w = threadIdx.x >> 6, lane = threadIdx.x & 63;
    const int nt = nb * 4 + w;

    f32x16 cre0, cim0, cre1, cim1;
#pragma unroll
    for (int q = 0; q < 16; ++q) { cre0[q] = 0.f; cim0[q] = 0.f; cre1[q] = 0.f; cim1[q] = 0.f; }

    const ushort_t* ab = xf + (size_t)cs * KB * 4096 + (size_t)lane * 8;
    const ushort_t* bb = kf + (size_t)cs * KB * 16384 + (size_t)nt * 1024 + (size_t)lane * 8;

    bf16x8 Brh = LDB(bb), Bih = LDB(bb + 512);
    bf16x8 Arh0 = LDB(ab), Arl0 = LDB(ab + 512), Aih0 = LDB(ab + 1024), Ail0 = LDB(ab + 1536);
    bf16x8 Arh1 = LDB(ab + 2048), Arl1 = LDB(ab + 2560), Aih1 = LDB(ab + 3072), Ail1 = LDB(ab + 3584);

    for (int kb = 0; kb < KB; ++kb) {
        const int kn = (kb + 1 < KB) ? kb + 1 : kb;
        const ushort_t* an = ab + (size_t)kn * 4096;
        const ushort_t* bn = bb + (size_t)kn * 16384;
        const bf16x8 nBrh = LDB(bn), nBih = LDB(bn + 512);
        const bf16x8 nArh0 = LDB(an), nArl0 = LDB(an + 512), nAih0 = LDB(an + 1024), nAil0 = LDB(an + 1536);
        const bf16x8 nArh1 = LDB(an + 2048), nArl1 = LDB(an + 2560), nAih1 = LDB(an + 3072), nAil1 = LDB(an + 3584);

        const bf16x8 NAih0 = bneg(Aih0), NAil0 = bneg(Ail0);
        const bf16x8 NAih1 = bneg(Aih1), NAil1 = bneg(Ail1);

        MFMA(cre0, Arh0, Brh); MFMA(cre0, Arl0, Brh);
        MFMA(cre0, NAih0, Bih); MFMA(cre0, NAil0, Bih);
        MFMA(cim0, Arh0, Bih); MFMA(cim0, Arl0, Bih);
        MFMA(cim0, Aih0, Brh); MFMA(cim0, Ail0, Brh);
        MFMA(cre1, Arh1, Brh); MFMA(cre1, Arl1, Brh);
        MFMA(cre1, NAih1, Bih); MFMA(cre1, NAil1, Bih);
        MFMA(cim1, Arh1, Bih); MFMA(cim1, Arl1, Bih);
        MFMA(cim1, Aih1, Brh); MFMA(cim1, Ail1, Brh);

        Brh = nBrh; Bih = nBih;
        Arh0 = nArh0; Arl0 = nArl0; Aih0 = nAih0; Ail0 = nAil0;
        Arh1 = nArh1; Arl1 = nArl1; Aih1 = nAih1; Ail1 = nAil1;
    }

    // C/D layout: col=lane&31, row=(reg&3)+8*(reg>>2)+4*(lane>>5)
    const int col = lane & 31, rhi = (lane >> 5) * 4;
    const int n = nb * 128 + w * 32 + col;
#pragma unroll
    for (int mt = 0; mt < 2; ++mt) {
        const f32x16 cr = mt ? cre1 : cre0;
        const f32x16 ci = mt ? cim1 : cim0;
#pragma unroll
        for (int reg = 0; reg < 16; ++reg) {
            const int row = (reg & 3) + 8 * (reg >> 2) + rhi;
            const size_t off = ((size_t)cs * B + mt * 32 + row) * 512 + n;
            float vr = cr[reg], vi = ci[reg];
            if (acc) { vr += yre[off]; vi += yim[off]; }
            yre[off] = vr; yim[off] = vi;
        }
    }
}

// ---------------------------------------------------------------------------
// ifft: mirror half-spectrum (cs = ky*9+kx, kx 0..8), 2D inverse DFT, +bias.
// ---------------------------------------------------------------------------
__global__ __launch_bounds__(256) void ifft_y_kernel(
    const float* __restrict__ yre, const float* __restrict__ yim,
    const float* __restrict__ bias, float* __restrict__ out)
{
    __shared__ float tw_r[16], tw_i[16];
    __shared__ float yr_s[NCS][17], yi_s[NCS][17];
    __shared__ float t_re[16][280], t_im[16][280];   // 280 % 32 == 24 -> 2-way max
    __shared__ float ost[2][256][9];
    const int tid = threadIdx.x;
    const int ng = blockIdx.x;   // 0..31
    const int b = blockIdx.y;
    const int n0 = ng * 16;
    if (tid < 16) { float s, c; sincosf(2.f * M_PIF * tid / 16.f, &s, &c); tw_r[tid] = c; tw_i[tid] = s; }
    for (int t = tid; t < NCS * 16; t += 256) {
        const int cs = t >> 4, nl = t & 15;
        const size_t off = ((size_t)cs * B + b) * 512 + n0 + nl;
        yr_s[cs][nl] = yre[off];
        yi_s[cs][nl] = yim[off];
    }
    __syncthreads();
    float twr[16], twi[16];
#pragma unroll
    for (int j = 0; j < 16; ++j) { twr[j] = tw_r[j]; twi[j] = tw_i[j]; }

    const int g = tid >> 4, l = tid & 15;

    // pass 1: row ky=l, reconstruct full kx via Hermitian mirror, iDFT over kx
    float Yr[16], Yi[16];
#pragma unroll
    for (int kx = 0; kx < 16; ++kx) {
        if (kx <= 8) {
            const int cs = l * 9 + kx;
            Yr[kx] = yr_s[cs][g]; Yi[kx] = yi_s[cs][g];
        } else {
            const int cs = ((16 - l) & 15) * 9 + (16 - kx);
            Yr[kx] = yr_s[cs][g]; Yi[kx] = -yi_s[cs][g];
        }
    }
#pragma unroll
    for (int sx = 0; sx < 16; ++sx) {
        float sr = 0.f, si = 0.f;
#pragma unroll
        for (int n = 0; n < 16; ++n) {
            const int j = (sx * n) & 15;
            sr = fmaf(Yr[n], twr[j], sr); sr = fmaf(-Yi[n], twi[j], sr);
            si = fmaf(Yr[n], twi[j], si); si = fmaf(Yi[n], twr[j], si);
        }
        t_re[g][sx * 17 + l] = sr;
        t_im[g][sx * 17 + l] = si;
    }
    __syncthreads();

    // pass 2: column sx=l, inverse DFT over ky, real part only
    float Tr[16], Ti[16];
#pragma unroll
    for (int n = 0; n < 16; ++n) { Tr[n] = t_re[g][l * 17 + n]; Ti[n] = t_im[g][l * 17 + n]; }
    const int fl = g >> 3, pq = g & 7;
#pragma unroll
    for (int sy = 0; sy < 16; ++sy) {
        float sr = 0.f;
#pragma unroll
        for (int n = 0; n < 16; ++n) {
            const int j = (sy * n) & 15;
            sr = fmaf(Tr[n], twr[j], sr); sr = fmaf(-Ti[n], twi[j], sr);
        }
        ost[fl][sy * 16 + l][pq] = sr * (1.f / 256.f);
    }
    __syncthreads();

    const int f0 = ng * 2;
    for (int t = tid; t < 4096; t += 256) {
        const int flv = t >> 11, e = t & 2047;
        out[((size_t)b * F + f0 + flv) * NS + e] = ost[flv][e >> 3][e & 7] + bias[f0 + flv];
    }
}

// ---------------------------------------------------------------------------
extern "C" void kernel_launch(void* const* d_in, const int* in_sizes, int n_in,
                              void* d_out, int out_size, void* d_ws, size_t ws_size,
                              hipStream_t stream)
{
    const float* x = (const float*)d_in[0];
    const float* kern = (const float*)d_in[1];
    const float* bias = (const float*)d_in[2];
    const int* pt = (const int*)d_in[3];
    float* out = (float*)d_out;

    // largest in-feature chunk CI that fits workspace
    int CI = 2;
    const int cands[6] = {64, 32, 16, 8, 4, 2};
    for (int t = 0; t < 6; ++t) {
        const int KBc = cands[t] / 2;
        const size_t need = 65536                          // pt2
                          + (size_t)NCS * KBc * 8192       // xf (4 planes bf16)
                          + (size_t)NCS * KBc * 32768      // kf (2 planes bf16)
                          + 2 * (size_t)NCS * B * 512 * 4; // yf re/im fp32
        if (need <= ws_size) { CI = cands[t]; break; }
    }
    const int KB = CI / 2;

    char* p = (char*)d_ws;
    int* pt2 = (int*)p;          p += 65536;
    ushort_t* xf = (ushort_t*)p; p += (size_t)NCS * KB * 8192;
    ushort_t* kf = (ushort_t*)p; p += (size_t)NCS * KB * 32768;
    float* yre = (float*)p;      p += (size_t)NCS * B * 512 * 4;
    float* yim = (float*)p;

    permute_pt_kernel<<<64, 256, 0, stream>>>(pt, pt2);

    const int nch = IFT / CI;
    for (int ch = 0; ch < nch; ++ch) {
        const int i0 = ch * CI;
        fft_x_kernel<<<dim3(32, CI), 256, 0, stream>>>(x, xf, i0, KB);
        fft_k_kernel<<<dim3(64, CI), 256, 0, stream>>>(kern, pt2, kf, i0, KB);
        gemm_kernel<<<dim3(4, NCS), 256, 0, stream>>>(xf, kf, yre, yim, KB, ch > 0);
    }
    ifft_y_kernel<<<dim3(32, B), 256, 0, stream>>>(yre, yim, bias, out);
}

// Round 4
// 351.944 us; speedup vs baseline: 2.8531x; 1.0369x over previous
//
#include <hip/hip_runtime.h>

typedef __attribute__((ext_vector_type(8))) short bf16x8;
typedef __attribute__((ext_vector_type(16))) float f32x16;
typedef unsigned short ushort_t;

constexpr int NS  = 2048;  // n_symm
constexpr int F   = 64;    // out features
constexpr int IFT = 64;    // in features
constexpr int B   = 64;    // batch
constexpr int NCS = 144;   // half-spectrum cells: cs = ky*9 + kx, kx in 0..8, ky in 0..15

// cos/sin(2*pi*j/16) — compile-time literal twiddles (zeros/±1 fold away)
constexpr float CT[16] = {
    1.0f,  0.9238795325112867f,  0.7071067811865476f,  0.3826834323650898f,
    0.0f, -0.3826834323650898f, -0.7071067811865476f, -0.9238795325112867f,
   -1.0f, -0.9238795325112867f, -0.7071067811865476f, -0.3826834323650898f,
    0.0f,  0.3826834323650898f,  0.7071067811865476f,  0.9238795325112867f};
constexpr float ST[16] = {
    0.0f,  0.3826834323650898f,  0.7071067811865476f,  0.9238795325112867f,
    1.0f,  0.9238795325112867f,  0.7071067811865476f,  0.3826834323650898f,
    0.0f, -0.3826834323650898f, -0.7071067811865476f, -0.9238795325112867f,
   -1.0f, -0.9238795325112867f, -0.7071067811865476f, -0.3826834323650898f};

__device__ inline ushort_t f2bf(float x) {
    unsigned u = __float_as_uint(x);
    unsigned r = u + 0x7FFFu + ((u >> 16) & 1u);
    return (ushort_t)(r >> 16);
}
__device__ inline float bf2f(ushort_t h) { return __uint_as_float(((unsigned)h) << 16); }

__device__ inline bf16x8 bneg(bf16x8 v) {
    union { bf16x8 b; unsigned u[4]; } x; x.b = v;
    x.u[0] ^= 0x80008000u; x.u[1] ^= 0x80008000u;
    x.u[2] ^= 0x80008000u; x.u[3] ^= 0x80008000u;
    return x.b;
}

// ---------------------------------------------------------------------------
// pt2[a][bq][s] = pt[a][s*8+bq]
// ---------------------------------------------------------------------------
__global__ __launch_bounds__(256) void permute_pt_kernel(
    const int* __restrict__ pt, int* __restrict__ pt2)
{
    const int t = blockIdx.x * 256 + threadIdx.x;   // 16384
    const int a = t >> 11, r = t & 2047;
    const int bq = r >> 8, s = r & 255;
    pt2[t] = pt[a * NS + s * 8 + bq];
}

// ---------------------------------------------------------------------------
// fft_x: x[b,i,s*8+a] -> A-fragments (bf16 hi/lo, re/im: 4 planes)
// xf[(((cs*KB+kb)*2+mt)*4+v)*512 + lane*8 + j]
//   A[m=lane&31][k16=(lane>>5)*8+j], m=b (mt=b>>5), k_local=il*8+a
// ---------------------------------------------------------------------------
__global__ __launch_bounds__(256, 4) void fft_x_kernel(
    const float* __restrict__ x, ushort_t* __restrict__ xf, int i0, int KB)
{
    __shared__ float t_re[16][152], t_im[16][152];   // 152 % 32 == 24 -> conflict-light
    __shared__ ushort_t stgx[NCS * 68];
    const int tid = threadIdx.x;
    const int bp = blockIdx.x;   // 0..31
    const int il = blockIdx.y;   // 0..CI-1

    const int g = tid >> 4, l = tid & 15;
    const int bloc = g & 1, a = g >> 1;
    const int b = bp * 2 + bloc;
    const int i = i0 + il;

    // pass 1: row sy=l, real DFT over sx, kx 0..8 (literal twiddles)
    const float* xr = x + ((size_t)b * IFT + i) * NS;
    float v[16];
#pragma unroll
    for (int sx = 0; sx < 16; ++sx) v[sx] = xr[(l * 16 + sx) * 8 + a];
#pragma unroll
    for (int kx = 0; kx < 9; ++kx) {
        float sr = 0.f, si = 0.f;
#pragma unroll
        for (int n = 0; n < 16; ++n) {
            const int j = (kx * n) & 15;
            sr = fmaf(v[n], CT[j], sr);
            si = fmaf(v[n], -ST[j], si);
        }
        t_re[g][kx * 17 + l] = sr;
        t_im[g][kx * 17 + l] = si;
    }
    __syncthreads();

    // pass 2: column kx=l (l<9), complex DFT over sy
    if (l < 9) {
        float Tr[16], Ti[16];
#pragma unroll
        for (int n = 0; n < 16; ++n) { Tr[n] = t_re[g][l * 17 + n]; Ti[n] = t_im[g][l * 17 + n]; }
#pragma unroll
        for (int ky = 0; ky < 16; ++ky) {
            float sr = 0.f, si = 0.f;
#pragma unroll
            for (int n = 0; n < 16; ++n) {
                const int j = (ky * n) & 15;
                sr = fmaf(Tr[n], CT[j], sr); sr = fmaf(Ti[n], ST[j], sr);
                si = fmaf(Ti[n], CT[j], si); si = fmaf(Tr[n], -ST[j], si);
            }
            const int cs = ky * 9 + l;
            const ushort_t rh = f2bf(sr); const ushort_t rl = f2bf(sr - bf2f(rh));
            const ushort_t ih = f2bf(si); const ushort_t ilo = f2bf(si - bf2f(ih));
            const unsigned w0 = (unsigned)rh | ((unsigned)rl << 16);
            const unsigned w1 = (unsigned)ih | ((unsigned)ilo << 16);
            *(uint2*)&stgx[cs * 68 + bloc * 32 + a * 4] = make_uint2(w0, w1);
        }
    }
    __syncthreads();

    // fragment assembly: v planes {rh,rl,ih,il}
    const int kb = il >> 1, mt = bp >> 4;
    const int lb = (il & 1) * 32 + (bp & 15) * 2;
    for (int t = tid; t < NCS * 8; t += 256) {
        const int cs = t >> 3, v4 = (t >> 1) & 3, h = t & 1;
        union { ushort_t s[8]; uint4 u; } tmp;
        const int base = cs * 68 + h * 32 + (v4 >> 1) * 2 + (v4 & 1);
#pragma unroll
        for (int j = 0; j < 8; ++j) tmp.s[j] = stgx[base + j * 4];
        const size_t off = ((((size_t)cs * KB + kb) * 2 + mt) * 4 + v4) * 512 + (size_t)(lb + h) * 8;
        *(uint4*)(xf + off) = tmp.u;
    }
}

// ---------------------------------------------------------------------------
// fft_k: gather kernel[f,i,pt[a][s*8+bq]] -> B-fragments, bf16 (2 planes re,im)
// kf[(((cs*KB+kb)*16+nt)*2+v)*512 + lane*8 + j]
//   B[k16=(lane>>5)*8+j][n=(lane&31)+nt*32], n=f*8+bq, k_local=il*8+a
// ---------------------------------------------------------------------------
__global__ __launch_bounds__(256, 4) void fft_k_kernel(
    const float* __restrict__ kern, const int* __restrict__ pt2,
    ushort_t* __restrict__ kf, int i0, int KB)
{
    __shared__ float krow[2048];
    __shared__ float t_re[16][152], t_im[16][152];
    __shared__ unsigned stgk[NCS * 18];
    const int tid = threadIdx.x;
    const int bx = blockIdx.x;   // 0..63: fg(4 f's) x bqp
    const int il = blockIdx.y;
    const int fg = bx >> 2, bqp = bx & 3;
    const int i = i0 + il;

    const int g = tid >> 4, l = tid & 15;
    const int bql = g & 1, a = g >> 1;
    const int bq = bqp * 2 + bql;

    // gather indices (constant across f-rounds)
    int idx[16];
    const int4* pp = (const int4*)(pt2 + ((a * 8 + bq) * 256 + l * 16));
#pragma unroll
    for (int q = 0; q < 4; ++q) {
        const int4 t4 = pp[q];
        idx[q * 4] = t4.x; idx[q * 4 + 1] = t4.y; idx[q * 4 + 2] = t4.z; idx[q * 4 + 3] = t4.w;
    }

    const int kb = il >> 1;
    for (int fr = 0; fr < 4; ++fr) {
        const int f = fg * 4 + fr;
        __syncthreads();
        {
            const float4* src = (const float4*)(kern + ((size_t)f * IFT + i) * NS);
            for (int u = tid; u < 512; u += 256) ((float4*)krow)[u] = src[u];
        }
        __syncthreads();

        // pass 1: row sy=l, gathered real DFT over sx, kx 0..8
        float v[16];
#pragma unroll
        for (int sx = 0; sx < 16; ++sx) v[sx] = krow[idx[sx]];
#pragma unroll
        for (int kx = 0; kx < 9; ++kx) {
            float sr = 0.f, si = 0.f;
#pragma unroll
            for (int n = 0; n < 16; ++n) {
                const int j = (kx * n) & 15;
                sr = fmaf(v[n], CT[j], sr);
                si = fmaf(v[n], -ST[j], si);
            }
            t_re[g][kx * 17 + l] = sr;
            t_im[g][kx * 17 + l] = si;
        }
        __syncthreads();

        // pass 2: column kx=l (l<9), complex DFT over sy; pack bf16 re/im
        if (l < 9) {
            float Tr[16], Ti[16];
#pragma unroll
            for (int n = 0; n < 16; ++n) { Tr[n] = t_re[g][l * 17 + n]; Ti[n] = t_im[g][l * 17 + n]; }
#pragma unroll
            for (int ky = 0; ky < 16; ++ky) {
                float sr = 0.f, si = 0.f;
#pragma unroll
                for (int n = 0; n < 16; ++n) {
                    const int j = (ky * n) & 15;
                    sr = fmaf(Tr[n], CT[j], sr); sr = fmaf(Ti[n], ST[j], sr);
                    si = fmaf(Ti[n], CT[j], si); si = fmaf(Tr[n], -ST[j], si);
                }
                const int cs = ky * 9 + l;
                stgk[cs * 18 + bql * 8 + a] = (unsigned)f2bf(sr) | ((unsigned)f2bf(si) << 16);
            }
        }
        __syncthreads();

        // fragment assembly: v planes {re, im}
        const int nt = f >> 2;
        const int lbase = (il & 1) * 32 + (f & 3) * 8 + bqp * 2;
        for (int t = tid; t < NCS * 2; t += 256) {
            const int cs = t >> 1, h = t & 1;
            const int base = cs * 18 + h * 8;
            unsigned w[8];
            *(uint2*)&w[0] = *(const uint2*)&stgk[base];
            *(uint2*)&w[2] = *(const uint2*)&stgk[base + 2];
            *(uint2*)&w[4] = *(const uint2*)&stgk[base + 4];
            *(uint2*)&w[6] = *(const uint2*)&stgk[base + 6];
            union { ushort_t s[8]; uint4 u; } lo, hi;
#pragma unroll
            for (int j = 0; j < 8; ++j) { lo.s[j] = (ushort_t)(w[j] & 0xffffu); hi.s[j] = (ushort_t)(w[j] >> 16); }
            const size_t off0 = ((((size_t)cs * KB + kb) * 16 + nt) * 2 + 0) * 512 + (size_t)(lbase + h) * 8;
            *(uint4*)(kf + off0) = lo.u;
            *(uint4*)(kf + off0 + 512) = hi.u;
        }
    }
}

// ---------------------------------------------------------------------------
// MFMA complex GEMM, A split-bf16 (hi/lo), B plain bf16, no LDS.
// Block: 256 thr = 4 waves; wave = M64 x N32; 16 mfma_32x32x16 per k16.
// ---------------------------------------------------------------------------
#define MFMA(acc, A, Bv) acc = __builtin_amdgcn_mfma_f32_32x32x16_bf16(A, Bv, acc, 0, 0, 0)
#define LDB(p) (*(const bf16x8*)(p))

__global__ __launch_bounds__(256) void gemm_kernel(
    const ushort_t* __restrict__ xf, const ushort_t* __restrict__ kf,
    float* __restrict__ yre, float* __restrict__ yim, int KB, int acc)
{
    const int cs = blockIdx.y, nb = blockIdx.x;
    const int w = threadIdx.x >> 6, lane = threadIdx.x & 63;
    const int nt = nb * 4 + w;

    f32x16 cre0, cim0, cre1, cim1;
#pragma unroll
    for (int q = 0; q < 16; ++q) { cre0[q] = 0.f; cim0[q] = 0.f; cre1[q] = 0.f; cim1[q] = 0.f; }

    const ushort_t* ab = xf + (size_t)cs * KB * 4096 + (size_t)lane * 8;
    const ushort_t* bb = kf + (size_t)cs * KB * 16384 + (size_t)nt * 1024 + (size_t)lane * 8;

    bf16x8 Brh = LDB(bb), Bih = LDB(bb + 512);
    bf16x8 Arh0 = LDB(ab), Arl0 = LDB(ab + 512), Aih0 = LDB(ab + 1024), Ail0 = LDB(ab + 1536);
    bf16x8 Arh1 = LDB(ab + 2048), Arl1 = LDB(ab + 2560), Aih1 = LDB(ab + 3072), Ail1 = LDB(ab + 3584);

    for (int kb = 0; kb < KB; ++kb) {
        const int kn = (kb + 1 < KB) ? kb + 1 : kb;
        const ushort_t* an = ab + (size_t)kn * 4096;
        const ushort_t* bn = bb + (size_t)kn * 16384;
        const bf16x8 nBrh = LDB(bn), nBih = LDB(bn + 512);
        const bf16x8 nArh0 = LDB(an), nArl0 = LDB(an + 512), nAih0 = LDB(an + 1024), nAil0 = LDB(an + 1536);
        const bf16x8 nArh1 = LDB(an + 2048), nArl1 = LDB(an + 2560), nAih1 = LDB(an + 3072), nAil1 = LDB(an + 3584);

        const bf16x8 NAih0 = bneg(Aih0), NAil0 = bneg(Ail0);
        const bf16x8 NAih1 = bneg(Aih1), NAil1 = bneg(Ail1);

        MFMA(cre0, Arh0, Brh); MFMA(cre0, Arl0, Brh);
        MFMA(cre0, NAih0, Bih); MFMA(cre0, NAil0, Bih);
        MFMA(cim0, Arh0, Bih); MFMA(cim0, Arl0, Bih);
        MFMA(cim0, Aih0, Brh); MFMA(cim0, Ail0, Brh);
        MFMA(cre1, Arh1, Brh); MFMA(cre1, Arl1, Brh);
        MFMA(cre1, NAih1, Bih); MFMA(cre1, NAil1, Bih);
        MFMA(cim1, Arh1, Bih); MFMA(cim1, Arl1, Bih);
        MFMA(cim1, Aih1, Brh); MFMA(cim1, Ail1, Brh);

        Brh = nBrh; Bih = nBih;
        Arh0 = nArh0; Arl0 = nArl0; Aih0 = nAih0; Ail0 = nAil0;
        Arh1 = nArh1; Arl1 = nArl1; Aih1 = nAih1; Ail1 = nAil1;
    }

    // C/D layout: col=lane&31, row=(reg&3)+8*(reg>>2)+4*(lane>>5)
    const int col = lane & 31, rhi = (lane >> 5) * 4;
    const int n = nb * 128 + w * 32 + col;
#pragma unroll
    for (int mt = 0; mt < 2; ++mt) {
        const f32x16 cr = mt ? cre1 : cre0;
        const f32x16 ci = mt ? cim1 : cim0;
#pragma unroll
        for (int reg = 0; reg < 16; ++reg) {
            const int row = (reg & 3) + 8 * (reg >> 2) + rhi;
            const size_t off = ((size_t)cs * B + mt * 32 + row) * 512 + n;
            float vr = cr[reg], vi = ci[reg];
            if (acc) { vr += yre[off]; vi += yim[off]; }
            yre[off] = vr; yim[off] = vi;
        }
    }
}

// ---------------------------------------------------------------------------
// ifft: mirror half-spectrum (cs = ky*9+kx, kx 0..8), 2D inverse DFT, +bias.
// ---------------------------------------------------------------------------
__global__ __launch_bounds__(256, 4) void ifft_y_kernel(
    const float* __restrict__ yre, const float* __restrict__ yim,
    const float* __restrict__ bias, float* __restrict__ out)
{
    __shared__ float yr_s[NCS][17], yi_s[NCS][17];
    __shared__ float t_re[16][271], t_im[16][271];
    __shared__ float ost[2][256][9];
    const int tid = threadIdx.x;
    const int ng = blockIdx.x;   // 0..31
    const int b = blockIdx.y;
    const int n0 = ng * 16;
    for (int t = tid; t < NCS * 16; t += 256) {
        const int cs = t >> 4, nl = t & 15;
        const size_t off = ((size_t)cs * B + b) * 512 + n0 + nl;
        yr_s[cs][nl] = yre[off];
        yi_s[cs][nl] = yim[off];
    }
    __syncthreads();

    const int g = tid >> 4, l = tid & 15;

    // pass 1: row ky=l, reconstruct full kx via Hermitian mirror, iDFT over kx
    float Yr[16], Yi[16];
#pragma unroll
    for (int kx = 0; kx < 16; ++kx) {
        if (kx <= 8) {
            const int cs = l * 9 + kx;
            Yr[kx] = yr_s[cs][g]; Yi[kx] = yi_s[cs][g];
        } else {
            const int cs = ((16 - l) & 15) * 9 + (16 - kx);
            Yr[kx] = yr_s[cs][g]; Yi[kx] = -yi_s[cs][g];
        }
    }
#pragma unroll
    for (int sx = 0; sx < 16; ++sx) {
        float sr = 0.f, si = 0.f;
#pragma unroll
        for (int n = 0; n < 16; ++n) {
            const int j = (sx * n) & 15;
            sr = fmaf(Yr[n], CT[j], sr); sr = fmaf(Yi[n], -ST[j], sr);
            si = fmaf(Yr[n], ST[j], si); si = fmaf(Yi[n], CT[j], si);
        }
        t_re[g][sx * 17 + l] = sr;
        t_im[g][sx * 17 + l] = si;
    }
    __syncthreads();

    // pass 2: column sx=l, inverse DFT over ky, real part only
    float Tr[16], Ti[16];
#pragma unroll
    for (int n = 0; n < 16; ++n) { Tr[n] = t_re[g][l * 17 + n]; Ti[n] = t_im[g][l * 17 + n]; }
    const int fl = g >> 3, pq = g & 7;
#pragma unroll
    for (int sy = 0; sy < 16; ++sy) {
        float sr = 0.f;
#pragma unroll
        for (int n = 0; n < 16; ++n) {
            const int j = (sy * n) & 15;
            sr = fmaf(Tr[n], CT[j], sr); sr = fmaf(Ti[n], -ST[j], sr);
        }
        ost[fl][sy * 16 + l][pq] = sr * (1.f / 256.f);
    }
    __syncthreads();

    const int f0 = ng * 2;
    for (int t = tid; t < 4096; t += 256) {
        const int flv = t >> 11, e = t & 2047;
        out[((size_t)b * F + f0 + flv) * NS + e] = ost[flv][e >> 3][e & 7] + bias[f0 + flv];
    }
}

// ---------------------------------------------------------------------------
extern "C" void kernel_launch(void* const* d_in, const int* in_sizes, int n_in,
                              void* d_out, int out_size, void* d_ws, size_t ws_size,
                              hipStream_t stream)
{
    const float* x = (const float*)d_in[0];
    const float* kern = (const float*)d_in[1];
    const float* bias = (const float*)d_in[2];
    const int* pt = (const int*)d_in[3];
    float* out = (float*)d_out;

    // largest in-feature chunk CI that fits workspace
    int CI = 2;
    const int cands[6] = {64, 32, 16, 8, 4, 2};
    for (int t = 0; t < 6; ++t) {
        const int KBc = cands[t] / 2;
        const size_t need = 65536                          // pt2
                          + (size_t)NCS * KBc * 8192       // xf (4 planes bf16)
                          + (size_t)NCS * KBc * 32768      // kf (2 planes bf16)
                          + 2 * (size_t)NCS * B * 512 * 4; // yf re/im fp32
        if (need <= ws_size) { CI = cands[t]; break; }
    }
    const int KB = CI / 2;

    char* p = (char*)d_ws;
    int* pt2 = (int*)p;          p += 65536;
    ushort_t* xf = (ushort_t*)p; p += (size_t)NCS * KB * 8192;
    ushort_t* kf = (ushort_t*)p; p += (size_t)NCS * KB * 32768;
    float* yre = (float*)p;      p += (size_t)NCS * B * 512 * 4;
    float* yim = (float*)p;

    permute_pt_kernel<<<64, 256, 0, stream>>>(pt, pt2);

    const int nch = IFT / CI;
    for (int ch = 0; ch < nch; ++ch) {
        const int i0 = ch * CI;
        fft_x_kernel<<<dim3(32, CI), 256, 0, stream>>>(x, xf, i0, KB);
        fft_k_kernel<<<dim3(64, CI), 256, 0, stream>>>(kern, pt2, kf, i0, KB);
        gemm_kernel<<<dim3(4, NCS), 256, 0, stream>>>(xf, kf, yre, yim, KB, ch > 0);
    }
    ifft_y_kernel<<<dim3(32, B), 256, 0, stream>>>(yre, yim, bias, out);
}

// Round 5
// 326.362 us; speedup vs baseline: 3.0768x; 1.0784x over previous
//
#include <hip/hip_runtime.h>

typedef __attribute__((ext_vector_type(8))) short bf16x8;
typedef __attribute__((ext_vector_type(16))) float f32x16;
typedef unsigned short ushort_t;

constexpr int NS  = 2048;  // n_symm
constexpr int F   = 64;    // out features
constexpr int IFT = 64;    // in features
constexpr int B   = 64;    // batch
constexpr int NCS = 144;   // half-spectrum cells: cs = ky*9 + kx, kx in 0..8, ky in 0..15

// cos/sin(2*pi*j/16)
constexpr float CT[16] = {
    1.0f,  0.9238795325112867f,  0.7071067811865476f,  0.3826834323650898f,
    0.0f, -0.3826834323650898f, -0.7071067811865476f, -0.9238795325112867f,
   -1.0f, -0.9238795325112867f, -0.7071067811865476f, -0.3826834323650898f,
    0.0f,  0.3826834323650898f,  0.7071067811865476f,  0.9238795325112867f};
constexpr float ST[16] = {
    0.0f,  0.3826834323650898f,  0.7071067811865476f,  0.9238795325112867f,
    1.0f,  0.9238795325112867f,  0.7071067811865476f,  0.3826834323650898f,
    0.0f, -0.3826834323650898f, -0.7071067811865476f, -0.9238795325112867f,
   -1.0f, -0.9238795325112867f, -0.7071067811865476f, -0.3826834323650898f};

// digit-reverse base 4: X[k] lives in slot DR4[k] after fft16
constexpr int DR4[16] = {0,4,8,12, 1,5,9,13, 2,6,10,14, 3,7,11,15};

// forward: X1 = t1 - i t3, X3 = t1 + i t3 ; inverse: swapped
template<bool INV>
__device__ inline void dft4(float& ar, float& ai, float& br, float& bi,
                            float& cr, float& ci, float& dr, float& di)
{
    const float t0r = ar + cr, t0i = ai + ci;
    const float t1r = ar - cr, t1i = ai - ci;
    const float t2r = br + dr, t2i = bi + di;
    const float t3r = br - dr, t3i = bi - di;
    ar = t0r + t2r; ai = t0i + t2i;
    cr = t0r - t2r; ci = t0i - t2i;
    if (!INV) { br = t1r + t3i; bi = t1i - t3r; dr = t1r - t3i; di = t1i + t3r; }
    else      { br = t1r - t3i; bi = t1i + t3r; dr = t1r + t3i; di = t1i - t3r; }
}

// radix-4 DIT FFT-16, in place, input natural order, output digit-reversed
// (consumer reads X[k] from slot DR4[k]).
template<bool INV>
__device__ inline void fft16(float* xr, float* xi)
{
#pragma unroll
    for (int r = 0; r < 4; ++r)
        dft4<INV>(xr[r], xi[r], xr[r + 4], xi[r + 4],
                  xr[r + 8], xi[r + 8], xr[r + 12], xi[r + 12]);
#pragma unroll
    for (int r = 1; r < 4; ++r)
#pragma unroll
        for (int q = 1; q < 4; ++q) {
            const int t = (r * q) & 15;
            const int s = r + 4 * q;
            if (t == 4) {   // multiply by -i (fwd) / +i (inv)
                const float tr = xr[s];
                if (!INV) { xr[s] = xi[s];  xi[s] = -tr; }
                else      { xr[s] = -xi[s]; xi[s] = tr;  }
            } else {
                const float c = CT[t], sn = INV ? ST[t] : -ST[t];
                const float tr = xr[s];
                xr[s] = tr * c - xi[s] * sn;
                xi[s] = tr * sn + xi[s] * c;
            }
        }
#pragma unroll
    for (int q = 0; q < 4; ++q)
        dft4<INV>(xr[4 * q], xi[4 * q], xr[4 * q + 1], xi[4 * q + 1],
                  xr[4 * q + 2], xi[4 * q + 2], xr[4 * q + 3], xi[4 * q + 3]);
}

__device__ inline ushort_t f2bf(float x) {
    unsigned u = __float_as_uint(x);
    unsigned r = u + 0x7FFFu + ((u >> 16) & 1u);
    return (ushort_t)(r >> 16);
}
__device__ inline float bf2f(ushort_t h) { return __uint_as_float(((unsigned)h) << 16); }

__device__ inline bf16x8 bneg(bf16x8 v) {
    union { bf16x8 b; unsigned u[4]; } x; x.b = v;
    x.u[0] ^= 0x80008000u; x.u[1] ^= 0x80008000u;
    x.u[2] ^= 0x80008000u; x.u[3] ^= 0x80008000u;
    return x.b;
}

// ---------------------------------------------------------------------------
// pt2[a][bq][s] = pt[a][s*8+bq]
// ---------------------------------------------------------------------------
__global__ __launch_bounds__(256) void permute_pt_kernel(
    const int* __restrict__ pt, int* __restrict__ pt2)
{
    const int t = blockIdx.x * 256 + threadIdx.x;   // 16384
    const int a = t >> 11, r = t & 2047;
    const int bq = r >> 8, s = r & 255;
    pt2[t] = pt[a * NS + s * 8 + bq];
}

// ---------------------------------------------------------------------------
// fft_x: x[b,i,s*8+a] -> A-fragments (bf16 hi/lo, re/im: 4 planes)
// xf[(((cs*KB+kb)*2+mt)*4+v)*512 + lane*8 + j]
// ---------------------------------------------------------------------------
__global__ __launch_bounds__(256, 4) void fft_x_kernel(
    const float* __restrict__ x, ushort_t* __restrict__ xf, int i0, int KB)
{
    __shared__ float t_re[16][152], t_im[16][152];
    __shared__ ushort_t stgx[NCS * 68];
    const int tid = threadIdx.x;
    const int bp = blockIdx.x;   // 0..31
    const int il = blockIdx.y;   // 0..CI-1

    const int g = tid >> 4, l = tid & 15;
    const int bloc = g & 1, a = g >> 1;
    const int b = bp * 2 + bloc;
    const int i = i0 + il;

    // pass 1: row sy=l, real-input FFT-16 over sx, keep kx 0..8
    const float* xr_g = x + ((size_t)b * IFT + i) * NS;
    float xr[16], xi[16];
#pragma unroll
    for (int sx = 0; sx < 16; ++sx) { xr[sx] = xr_g[(l * 16 + sx) * 8 + a]; xi[sx] = 0.f; }
    fft16<false>(xr, xi);
#pragma unroll
    for (int kx = 0; kx < 9; ++kx) {
        t_re[g][kx * 17 + l] = xr[DR4[kx]];
        t_im[g][kx * 17 + l] = xi[DR4[kx]];
    }
    __syncthreads();

    // pass 2: column kx=l (l<9), complex FFT-16 over sy
    if (l < 9) {
        float Tr[16], Ti[16];
#pragma unroll
        for (int n = 0; n < 16; ++n) { Tr[n] = t_re[g][l * 17 + n]; Ti[n] = t_im[g][l * 17 + n]; }
        fft16<false>(Tr, Ti);
#pragma unroll
        for (int ky = 0; ky < 16; ++ky) {
            const float sr = Tr[DR4[ky]], si = Ti[DR4[ky]];
            const int cs = ky * 9 + l;
            const ushort_t rh = f2bf(sr); const ushort_t rl = f2bf(sr - bf2f(rh));
            const ushort_t ih = f2bf(si); const ushort_t ilo = f2bf(si - bf2f(ih));
            const unsigned w0 = (unsigned)rh | ((unsigned)rl << 16);
            const unsigned w1 = (unsigned)ih | ((unsigned)ilo << 16);
            *(uint2*)&stgx[cs * 68 + bloc * 32 + a * 4] = make_uint2(w0, w1);
        }
    }
    __syncthreads();

    // fragment assembly: v planes {rh,rl,ih,il}
    const int kb = il >> 1, mt = bp >> 4;
    const int lb = (il & 1) * 32 + (bp & 15) * 2;
    for (int t = tid; t < NCS * 8; t += 256) {
        const int cs = t >> 3, v4 = (t >> 1) & 3, h = t & 1;
        union { ushort_t s[8]; uint4 u; } tmp;
        const int base = cs * 68 + h * 32 + (v4 >> 1) * 2 + (v4 & 1);
#pragma unroll
        for (int j = 0; j < 8; ++j) tmp.s[j] = stgx[base + j * 4];
        const size_t off = ((((size_t)cs * KB + kb) * 2 + mt) * 4 + v4) * 512 + (size_t)(lb + h) * 8;
        *(uint4*)(xf + off) = tmp.u;
    }
}

// ---------------------------------------------------------------------------
// fft_k: gather kernel[f,i,pt[a][s*8+bq]] -> B-fragments, bf16 (2 planes re,im)
// kf[(((cs*KB+kb)*16+nt)*2+v)*512 + lane*8 + j]
// ---------------------------------------------------------------------------
__global__ __launch_bounds__(256, 4) void fft_k_kernel(
    const float* __restrict__ kern, const int* __restrict__ pt2,
    ushort_t* __restrict__ kf, int i0, int KB)
{
    __shared__ float krow[2048];
    __shared__ float t_re[16][152], t_im[16][152];
    __shared__ unsigned stgk[NCS * 18];
    const int tid = threadIdx.x;
    const int bx = blockIdx.x;   // 0..63: fg(4 f's) x bqp
    const int il = blockIdx.y;
    const int fg = bx >> 2, bqp = bx & 3;
    const int i = i0 + il;

    const int g = tid >> 4, l = tid & 15;
    const int bql = g & 1, a = g >> 1;
    const int bq = bqp * 2 + bql;

    // gather indices (constant across f-rounds)
    int idx[16];
    const int4* pp = (const int4*)(pt2 + ((a * 8 + bq) * 256 + l * 16));
#pragma unroll
    for (int q = 0; q < 4; ++q) {
        const int4 t4 = pp[q];
        idx[q * 4] = t4.x; idx[q * 4 + 1] = t4.y; idx[q * 4 + 2] = t4.z; idx[q * 4 + 3] = t4.w;
    }

    const int kb = il >> 1;
    for (int fr = 0; fr < 4; ++fr) {
        const int f = fg * 4 + fr;
        __syncthreads();
        {
            const float4* src = (const float4*)(kern + ((size_t)f * IFT + i) * NS);
            for (int u = tid; u < 512; u += 256) ((float4*)krow)[u] = src[u];
        }
        __syncthreads();

        // pass 1: row sy=l, gathered real-input FFT-16, keep kx 0..8
        float xr[16], xi[16];
#pragma unroll
        for (int sx = 0; sx < 16; ++sx) { xr[sx] = krow[idx[sx]]; xi[sx] = 0.f; }
        fft16<false>(xr, xi);
#pragma unroll
        for (int kx = 0; kx < 9; ++kx) {
            t_re[g][kx * 17 + l] = xr[DR4[kx]];
            t_im[g][kx * 17 + l] = xi[DR4[kx]];
        }
        __syncthreads();

        // pass 2: column kx=l (l<9), complex FFT-16; pack bf16 re/im
        if (l < 9) {
            float Tr[16], Ti[16];
#pragma unroll
            for (int n = 0; n < 16; ++n) { Tr[n] = t_re[g][l * 17 + n]; Ti[n] = t_im[g][l * 17 + n]; }
            fft16<false>(Tr, Ti);
#pragma unroll
            for (int ky = 0; ky < 16; ++ky) {
                const int cs = ky * 9 + l;
                stgk[cs * 18 + bql * 8 + a] =
                    (unsigned)f2bf(Tr[DR4[ky]]) | ((unsigned)f2bf(Ti[DR4[ky]]) << 16);
            }
        }
        __syncthreads();

        // fragment assembly: v planes {re, im}
        const int nt = f >> 2;
        const int lbase = (il & 1) * 32 + (f & 3) * 8 + bqp * 2;
        for (int t = tid; t < NCS * 2; t += 256) {
            const int cs = t >> 1, h = t & 1;
            const int base = cs * 18 + h * 8;
            unsigned w[8];
            *(uint2*)&w[0] = *(const uint2*)&stgk[base];
            *(uint2*)&w[2] = *(const uint2*)&stgk[base + 2];
            *(uint2*)&w[4] = *(const uint2*)&stgk[base + 4];
            *(uint2*)&w[6] = *(const uint2*)&stgk[base + 6];
            union { ushort_t s[8]; uint4 u; } lo, hi;
#pragma unroll
            for (int j = 0; j < 8; ++j) { lo.s[j] = (ushort_t)(w[j] & 0xffffu); hi.s[j] = (ushort_t)(w[j] >> 16); }
            const size_t off0 = ((((size_t)cs * KB + kb) * 16 + nt) * 2 + 0) * 512 + (size_t)(lbase + h) * 8;
            *(uint4*)(kf + off0) = lo.u;
            *(uint4*)(kf + off0 + 512) = hi.u;
        }
    }
}

// ---------------------------------------------------------------------------
// MFMA complex GEMM, A split-bf16 (hi/lo), B plain bf16, no LDS.
// ---------------------------------------------------------------------------
#define MFMA(acc, A, Bv) acc = __builtin_amdgcn_mfma_f32_32x32x16_bf16(A, Bv, acc, 0, 0, 0)
#define LDB(p) (*(const bf16x8*)(p))

__global__ __launch_bounds__(256) void gemm_kernel(
    const ushort_t* __restrict__ xf, const ushort_t* __restrict__ kf,
    float* __restrict__ yre, float* __restrict__ yim, int KB, int acc)
{
    const int cs = blockIdx.y, nb = blockIdx.x;
    const int w = threadIdx.x >> 6, lane = threadIdx.x & 63;
    const int nt = nb * 4 + w;

    f32x16 cre0, cim0, cre1, cim1;
#pragma unroll
    for (int q = 0; q < 16; ++q) { cre0[q] = 0.f; cim0[q] = 0.f; cre1[q] = 0.f; cim1[q] = 0.f; }

    const ushort_t* ab = xf + (size_t)cs * KB * 4096 + (size_t)lane * 8;
    const ushort_t* bb = kf + (size_t)cs * KB * 16384 + (size_t)nt * 1024 + (size_t)lane * 8;

    bf16x8 Brh = LDB(bb), Bih = LDB(bb + 512);
    bf16x8 Arh0 = LDB(ab), Arl0 = LDB(ab + 512), Aih0 = LDB(ab + 1024), Ail0 = LDB(ab + 1536);
    bf16x8 Arh1 = LDB(ab + 2048), Arl1 = LDB(ab + 2560), Aih1 = LDB(ab + 3072), Ail1 = LDB(ab + 3584);

    for (int kb = 0; kb < KB; ++kb) {
        const int kn = (kb + 1 < KB) ? kb + 1 : kb;
        const ushort_t* an = ab + (size_t)kn * 4096;
        const ushort_t* bn = bb + (size_t)kn * 16384;
        const bf16x8 nBrh = LDB(bn), nBih = LDB(bn + 512);
        const bf16x8 nArh0 = LDB(an), nArl0 = LDB(an + 512), nAih0 = LDB(an + 1024), nAil0 = LDB(an + 1536);
        const bf16x8 nArh1 = LDB(an + 2048), nArl1 = LDB(an + 2560), nAih1 = LDB(an + 3072), nAil1 = LDB(an + 3584);

        const bf16x8 NAih0 = bneg(Aih0), NAil0 = bneg(Ail0);
        const bf16x8 NAih1 = bneg(Aih1), NAil1 = bneg(Ail1);

        MFMA(cre0, Arh0, Brh); MFMA(cre0, Arl0, Brh);
        MFMA(cre0, NAih0, Bih); MFMA(cre0, NAil0, Bih);
        MFMA(cim0, Arh0, Bih); MFMA(cim0, Arl0, Bih);
        MFMA(cim0, Aih0, Brh); MFMA(cim0, Ail0, Brh);
        MFMA(cre1, Arh1, Brh); MFMA(cre1, Arl1, Brh);
        MFMA(cre1, NAih1, Bih); MFMA(cre1, NAil1, Bih);
        MFMA(cim1, Arh1, Bih); MFMA(cim1, Arl1, Bih);
        MFMA(cim1, Aih1, Brh); MFMA(cim1, Ail1, Brh);

        Brh = nBrh; Bih = nBih;
        Arh0 = nArh0; Arl0 = nArl0; Aih0 = nAih0; Ail0 = nAil0;
        Arh1 = nArh1; Arl1 = nArl1; Aih1 = nAih1; Ail1 = nAil1;
    }

    // C/D layout: col=lane&31, row=(reg&3)+8*(reg>>2)+4*(lane>>5)
    const int col = lane & 31, rhi = (lane >> 5) * 4;
    const int n = nb * 128 + w * 32 + col;
#pragma unroll
    for (int mt = 0; mt < 2; ++mt) {
        const f32x16 cr = mt ? cre1 : cre0;
        const f32x16 ci = mt ? cim1 : cim0;
#pragma unroll
        for (int reg = 0; reg < 16; ++reg) {
            const int row = (reg & 3) + 8 * (reg >> 2) + rhi;
            const size_t off = ((size_t)cs * B + mt * 32 + row) * 512 + n;
            float vr = cr[reg], vi = ci[reg];
            if (acc) { vr += yre[off]; vi += yim[off]; }
            yre[off] = vr; yim[off] = vi;
        }
    }
}

// ---------------------------------------------------------------------------
// ifft: mirror half-spectrum (cs = ky*9+kx), 2D inverse FFT, +bias.
// ---------------------------------------------------------------------------
__global__ __launch_bounds__(256, 4) void ifft_y_kernel(
    const float* __restrict__ yre, const float* __restrict__ yim,
    const float* __restrict__ bias, float* __restrict__ out)
{
    __shared__ float yr_s[NCS][17], yi_s[NCS][17];
    __shared__ float t_re[16][271], t_im[16][271];
    __shared__ float ost[2][256][9];
    const int tid = threadIdx.x;
    const int ng = blockIdx.x;   // 0..31
    const int b = blockIdx.y;
    const int n0 = ng * 16;
    for (int t = tid; t < NCS * 16; t += 256) {
        const int cs = t >> 4, nl = t & 15;
        const size_t off = ((size_t)cs * B + b) * 512 + n0 + nl;
        yr_s[cs][nl] = yre[off];
        yi_s[cs][nl] = yim[off];
    }
    __syncthreads();

    const int g = tid >> 4, l = tid & 15;

    // pass 1: row ky=l, Hermitian mirror, inverse FFT-16 over kx
    float Yr[16], Yi[16];
#pragma unroll
    for (int kx = 0; kx < 16; ++kx) {
        if (kx <= 8) {
            const int cs = l * 9 + kx;
            Yr[kx] = yr_s[cs][g]; Yi[kx] = yi_s[cs][g];
        } else {
            const int cs = ((16 - l) & 15) * 9 + (16 - kx);
            Yr[kx] = yr_s[cs][g]; Yi[kx] = -yi_s[cs][g];
        }
    }
    fft16<true>(Yr, Yi);
#pragma unroll
    for (int sx = 0; sx < 16; ++sx) {
        t_re[g][sx * 17 + l] = Yr[DR4[sx]];
        t_im[g][sx * 17 + l] = Yi[DR4[sx]];
    }
    __syncthreads();

    // pass 2: column sx=l, inverse FFT-16 over ky, real part only
    float Tr[16], Ti[16];
#pragma unroll
    for (int n = 0; n < 16; ++n) { Tr[n] = t_re[g][l * 17 + n]; Ti[n] = t_im[g][l * 17 + n]; }
    fft16<true>(Tr, Ti);
    const int fl = g >> 3, pq = g & 7;
#pragma unroll
    for (int sy = 0; sy < 16; ++sy)
        ost[fl][sy * 16 + l][pq] = Tr[DR4[sy]] * (1.f / 256.f);
    __syncthreads();

    const int f0 = ng * 2;
    for (int t = tid; t < 4096; t += 256) {
        const int flv = t >> 11, e = t & 2047;
        out[((size_t)b * F + f0 + flv) * NS + e] = ost[flv][e >> 3][e & 7] + bias[f0 + flv];
    }
}

// ---------------------------------------------------------------------------
extern "C" void kernel_launch(void* const* d_in, const int* in_sizes, int n_in,
                              void* d_out, int out_size, void* d_ws, size_t ws_size,
                              hipStream_t stream)
{
    const float* x = (const float*)d_in[0];
    const float* kern = (const float*)d_in[1];
    const float* bias = (const float*)d_in[2];
    const int* pt = (const int*)d_in[3];
    float* out = (float*)d_out;

    // largest in-feature chunk CI that fits workspace
    int CI = 2;
    const int cands[6] = {64, 32, 16, 8, 4, 2};
    for (int t = 0; t < 6; ++t) {
        const int KBc = cands[t] / 2;
        const size_t need = 65536                          // pt2
                          + (size_t)NCS * KBc * 8192       // xf (4 planes bf16)
                          + (size_t)NCS * KBc * 32768      // kf (2 planes bf16)
                          + 2 * (size_t)NCS * B * 512 * 4; // yf re/im fp32
        if (need <= ws_size) { CI = cands[t]; break; }
    }
    const int KB = CI / 2;

    char* p = (char*)d_ws;
    int* pt2 = (int*)p;          p += 65536;
    ushort_t* xf = (ushort_t*)p; p += (size_t)NCS * KB * 8192;
    ushort_t* kf = (ushort_t*)p; p += (size_t)NCS * KB * 32768;
    float* yre = (float*)p;      p += (size_t)NCS * B * 512 * 4;
    float* yim = (float*)p;

    permute_pt_kernel<<<64, 256, 0, stream>>>(pt, pt2);

    const int nch = IFT / CI;
    for (int ch = 0; ch < nch; ++ch) {
        const int i0 = ch * CI;
        fft_x_kernel<<<dim3(32, CI), 256, 0, stream>>>(x, xf, i0, KB);
        fft_k_kernel<<<dim3(64, CI), 256, 0, stream>>>(kern, pt2, kf, i0, KB);
        gemm_kernel<<<dim3(4, NCS), 256, 0, stream>>>(xf, kf, yre, yim, KB, ch > 0);
    }
    ifft_y_kernel<<<dim3(32, B), 256, 0, stream>>>(yre, yim, bias, out);
}

// Round 6
// 290.933 us; speedup vs baseline: 3.4514x; 1.1218x over previous
//
#include <hip/hip_runtime.h>

typedef __attribute__((ext_vector_type(8))) short bf16x8;
typedef __attribute__((ext_vector_type(16))) float f32x16;
typedef unsigned short ushort_t;

constexpr int NS  = 2048;  // n_symm
constexpr int F   = 64;    // out features
constexpr int IFT = 64;    // in features
constexpr int B   = 64;    // batch
constexpr int NCS = 144;   // half-spectrum cells: cs = ky*9 + kx, kx in 0..8, ky in 0..15

// cos/sin(2*pi*j/16)
constexpr float CT[16] = {
    1.0f,  0.9238795325112867f,  0.7071067811865476f,  0.3826834323650898f,
    0.0f, -0.3826834323650898f, -0.7071067811865476f, -0.9238795325112867f,
   -1.0f, -0.9238795325112867f, -0.7071067811865476f, -0.3826834323650898f,
    0.0f,  0.3826834323650898f,  0.7071067811865476f,  0.9238795325112867f};
constexpr float ST[16] = {
    0.0f,  0.3826834323650898f,  0.7071067811865476f,  0.9238795325112867f,
    1.0f,  0.9238795325112867f,  0.7071067811865476f,  0.3826834323650898f,
    0.0f, -0.3826834323650898f, -0.7071067811865476f, -0.9238795325112867f,
   -1.0f, -0.9238795325112867f, -0.7071067811865476f, -0.3826834323650898f};

// digit-reverse base 4: X[k] lives in slot DR4[k] after fft16
constexpr int DR4[16] = {0,4,8,12, 1,5,9,13, 2,6,10,14, 3,7,11,15};

template<bool INV>
__device__ inline void dft4(float& ar, float& ai, float& br, float& bi,
                            float& cr, float& ci, float& dr, float& di)
{
    const float t0r = ar + cr, t0i = ai + ci;
    const float t1r = ar - cr, t1i = ai - ci;
    const float t2r = br + dr, t2i = bi + di;
    const float t3r = br - dr, t3i = bi - di;
    ar = t0r + t2r; ai = t0i + t2i;
    cr = t0r - t2r; ci = t0i - t2i;
    if (!INV) { br = t1r + t3i; bi = t1i - t3r; dr = t1r - t3i; di = t1i + t3r; }
    else      { br = t1r - t3i; bi = t1i + t3r; dr = t1r + t3i; di = t1i - t3r; }
}

// radix-4 DIT FFT-16, in place, natural input, digit-reversed output (slot DR4[k]).
template<bool INV>
__device__ inline void fft16(float* xr, float* xi)
{
#pragma unroll
    for (int r = 0; r < 4; ++r)
        dft4<INV>(xr[r], xi[r], xr[r + 4], xi[r + 4],
                  xr[r + 8], xi[r + 8], xr[r + 12], xi[r + 12]);
#pragma unroll
    for (int r = 1; r < 4; ++r)
#pragma unroll
        for (int q = 1; q < 4; ++q) {
            const int t = (r * q) & 15;
            const int s = r + 4 * q;
            if (t == 4) {
                const float tr = xr[s];
                if (!INV) { xr[s] = xi[s];  xi[s] = -tr; }
                else      { xr[s] = -xi[s]; xi[s] = tr;  }
            } else {
                const float c = CT[t], sn = INV ? ST[t] : -ST[t];
                const float tr = xr[s];
                xr[s] = tr * c - xi[s] * sn;
                xi[s] = tr * sn + xi[s] * c;
            }
        }
#pragma unroll
    for (int q = 0; q < 4; ++q)
        dft4<INV>(xr[4 * q], xi[4 * q], xr[4 * q + 1], xi[4 * q + 1],
                  xr[4 * q + 2], xi[4 * q + 2], xr[4 * q + 3], xi[4 * q + 3]);
}

__device__ inline ushort_t f2bf(float x) {
    unsigned u = __float_as_uint(x);
    unsigned r = u + 0x7FFFu + ((u >> 16) & 1u);
    return (ushort_t)(r >> 16);
}
__device__ inline float bf2f(ushort_t h) { return __uint_as_float(((unsigned)h) << 16); }

__device__ inline bf16x8 bneg(bf16x8 v) {
    union { bf16x8 b; unsigned u[4]; } x; x.b = v;
    x.u[0] ^= 0x80008000u; x.u[1] ^= 0x80008000u;
    x.u[2] ^= 0x80008000u; x.u[3] ^= 0x80008000u;
    return x.b;
}

// ---------------------------------------------------------------------------
// pt2[a][bq][s] = pt[a][s*8+bq]
// ---------------------------------------------------------------------------
__global__ __launch_bounds__(256) void permute_pt_kernel(
    const int* __restrict__ pt, int* __restrict__ pt2)
{
    const int t = blockIdx.x * 256 + threadIdx.x;   // 16384
    const int a = t >> 11, r = t & 2047;
    const int bq = r >> 8, s = r & 255;
    pt2[t] = pt[a * NS + s * 8 + bq];
}

// ---------------------------------------------------------------------------
// fft_x: x[b,i,s*8+a] -> A-fragments, plane-major:
// xf[(kb*8 + mt*4 + v)*NCS*512 + cs*512 + lane*8 + j], v in {rh,rl,ih,il}
// ---------------------------------------------------------------------------
__global__ __launch_bounds__(256, 4) void fft_x_kernel(
    const float* __restrict__ x, ushort_t* __restrict__ xf, int i0, int KB)
{
    __shared__ float t_re[16][152], t_im[16][152];
    __shared__ ushort_t stgx[NCS * 68];
    const int tid = threadIdx.x;
    const int bp = blockIdx.x;   // 0..31
    const int il = blockIdx.y;   // 0..CI-1

    const int g = tid >> 4, l = tid & 15;
    const int bloc = g & 1, a = g >> 1;
    const int b = bp * 2 + bloc;
    const int i = i0 + il;

    // pass 1: row sy=l, real-input FFT-16 over sx, keep kx 0..8
    const float* xr_g = x + ((size_t)b * IFT + i) * NS;
    float xr[16], xi[16];
#pragma unroll
    for (int sx = 0; sx < 16; ++sx) { xr[sx] = xr_g[(l * 16 + sx) * 8 + a]; xi[sx] = 0.f; }
    fft16<false>(xr, xi);
#pragma unroll
    for (int kx = 0; kx < 9; ++kx) {
        t_re[g][kx * 17 + l] = xr[DR4[kx]];
        t_im[g][kx * 17 + l] = xi[DR4[kx]];
    }
    __syncthreads();

    // pass 2: column kx=l (l<9), complex FFT-16 over sy
    if (l < 9) {
        float Tr[16], Ti[16];
#pragma unroll
        for (int n = 0; n < 16; ++n) { Tr[n] = t_re[g][l * 17 + n]; Ti[n] = t_im[g][l * 17 + n]; }
        fft16<false>(Tr, Ti);
#pragma unroll
        for (int ky = 0; ky < 16; ++ky) {
            const float sr = Tr[DR4[ky]], si = Ti[DR4[ky]];
            const int cs = ky * 9 + l;
            const ushort_t rh = f2bf(sr); const ushort_t rl = f2bf(sr - bf2f(rh));
            const ushort_t ih = f2bf(si); const ushort_t ilo = f2bf(si - bf2f(ih));
            const unsigned w0 = (unsigned)rh | ((unsigned)rl << 16);
            const unsigned w1 = (unsigned)ih | ((unsigned)ilo << 16);
            *(uint2*)&stgx[cs * 68 + bloc * 32 + a * 4] = make_uint2(w0, w1);
        }
    }
    __syncthreads();

    // fragment assembly, plane-major write
    const int kb = il >> 1, mt = bp >> 4;
    const int lb = (il & 1) * 32 + (bp & 15) * 2;
    const size_t PS = (size_t)NCS * 512;
    for (int t = tid; t < NCS * 8; t += 256) {
        const int cs = t >> 3, v4 = (t >> 1) & 3, h = t & 1;
        union { ushort_t s[8]; uint4 u; } tmp;
        const int base = cs * 68 + h * 32 + v4;
#pragma unroll
        for (int j = 0; j < 8; ++j) tmp.s[j] = stgx[base + j * 4];
        const size_t off = (size_t)(kb * 8 + mt * 4 + v4) * PS + (size_t)cs * 512 + (size_t)(lb + h) * 8;
        *(uint4*)(xf + off) = tmp.u;
    }
}

// ---------------------------------------------------------------------------
// fft_k: gather kernel[f,i,pt[a][s*8+bq]] -> B-fragments, plane-major:
// kf[(kb*32 + nt*2 + v)*NCS*512 + cs*512 + lane*8 + j], v in {re, im}
// Paired-f rounds: 2 f's gathered per b64 from interleaved krow2.
// stgk overlays krow2 (disjoint live ranges). Packed pass-2 (144 threads).
// ---------------------------------------------------------------------------
__global__ __launch_bounds__(256, 4) void fft_k_kernel(
    const float* __restrict__ kern, const int* __restrict__ pt2,
    ushort_t* __restrict__ kf, int i0, int KB)
{
    __shared__ __align__(16) unsigned uni[4096];   // 16 KB: krow2 (float2[2048]) U stgk (unsigned[2592])
    __shared__ __align__(16) float2 t2[16 * 153];  // 19.6 KB
    float2* krow2 = reinterpret_cast<float2*>(uni);
    unsigned* stgk = uni;

    const int tid = threadIdx.x;
    const int fg  = blockIdx.x & 15;   // slow-varying f-group for XCD locality
    const int bqp = blockIdx.x >> 4;
    const int il  = blockIdx.y;
    const int i   = i0 + il;

    const int g = tid >> 4, l = tid & 15;
    const int bql = g & 1, a = g >> 1;
    const int bq  = bqp * 2 + bql;

    // gather indices (constant across rounds)
    int idx[16];
    const int4* pp = (const int4*)(pt2 + ((a * 8 + bq) * 256 + l * 16));
#pragma unroll
    for (int q = 0; q < 4; ++q) {
        const int4 t4 = pp[q];
        idx[q * 4] = t4.x; idx[q * 4 + 1] = t4.y; idx[q * 4 + 2] = t4.z; idx[q * 4 + 3] = t4.w;
    }

    const int kb = il >> 1;
    const int nt = fg;
    // packed pass-2 mapping: column job tid<144 -> transform pg, column pl
    const int pg = (tid * 57) >> 9;       // tid/9 for tid<144
    const int pl = tid - pg * 9;
    const int slot = (pg & 1) * 8 + (pg >> 1);
    const size_t PS = (size_t)NCS * 512;

    for (int fr2 = 0; fr2 < 2; ++fr2) {
        const int f0 = fg * 4 + fr2 * 2;
        __syncthreads();   // prior stgk reads complete before krow2 overwrite
        {
            const float4* s0 = (const float4*)(kern + ((size_t)f0 * IFT + i) * NS);
            const float4* s1 = (const float4*)(kern + ((size_t)(f0 + 1) * IFT + i) * NS);
            for (int u = tid; u < 512; u += 256) {
                const float4 va = s0[u], vb = s1[u];
                float4* dst = (float4*)(krow2 + (size_t)u * 4);
                dst[0] = make_float4(va.x, vb.x, va.y, vb.y);
                dst[1] = make_float4(va.z, vb.z, va.w, vb.w);
            }
        }
        __syncthreads();
        float2 v2[16];
#pragma unroll
        for (int sx = 0; sx < 16; ++sx) v2[sx] = krow2[idx[sx]];

        for (int sub = 0; sub < 2; ++sub) {
            // pass 1 from registers: real FFT-16 over sx, rows sy=l, keep kx 0..8
            {
                float xr[16], xi[16];
#pragma unroll
                for (int sx = 0; sx < 16; ++sx) { xr[sx] = sub ? v2[sx].y : v2[sx].x; xi[sx] = 0.f; }
                fft16<false>(xr, xi);
#pragma unroll
                for (int kx = 0; kx < 9; ++kx)
                    t2[g * 153 + kx * 17 + l] = make_float2(xr[DR4[kx]], xi[DR4[kx]]);
            }
            __syncthreads();   // t2 ready; all gathers done -> stgk region free

            // pass 2 packed: complex FFT-16 over sy, 144 active threads
            if (tid < 144) {
                float Tr[16], Ti[16];
#pragma unroll
                for (int n = 0; n < 16; ++n) {
                    const float2 tv = t2[pg * 153 + pl * 17 + n];
                    Tr[n] = tv.x; Ti[n] = tv.y;
                }
                fft16<false>(Tr, Ti);
#pragma unroll
                for (int ky = 0; ky < 16; ++ky) {
                    const int cs = ky * 9 + pl;
                    stgk[cs * 18 + slot] =
                        (unsigned)f2bf(Tr[DR4[ky]]) | ((unsigned)f2bf(Ti[DR4[ky]]) << 16);
                }
            }
            __syncthreads();

            // fragment assembly, plane-major write (wave footprint ~32 KB)
            const int f = f0 + sub;
            const int lbase = (il & 1) * 32 + (f & 3) * 8 + bqp * 2;
            for (int t = tid; t < NCS * 2; t += 256) {
                const int cs = t >> 1, h = t & 1;
                const int base = cs * 18 + h * 8;
                unsigned w[8];
                *(uint2*)&w[0] = *(const uint2*)&stgk[base];
                *(uint2*)&w[2] = *(const uint2*)&stgk[base + 2];
                *(uint2*)&w[4] = *(const uint2*)&stgk[base + 4];
                *(uint2*)&w[6] = *(const uint2*)&stgk[base + 6];
                union { ushort_t s[8]; uint4 u; } lo, hi;
#pragma unroll
                for (int j = 0; j < 8; ++j) { lo.s[j] = (ushort_t)(w[j] & 0xffffu); hi.s[j] = (ushort_t)(w[j] >> 16); }
                const size_t off = (size_t)(kb * 32 + nt * 2) * PS + (size_t)cs * 512 + (size_t)(lbase + h) * 8;
                *(uint4*)(kf + off) = lo.u;
                *(uint4*)(kf + off + PS) = hi.u;
            }
            __syncthreads();
        }
    }
}

// ---------------------------------------------------------------------------
// MFMA complex GEMM, A split-bf16 (hi/lo), B plain bf16, no LDS.
// Plane-major operands; grid (NCS, 4) so same-cs blocks share an XCD (A in L2).
// ---------------------------------------------------------------------------
#define MFMA(acc, A, Bv) acc = __builtin_amdgcn_mfma_f32_32x32x16_bf16(A, Bv, acc, 0, 0, 0)
#define LDB(p) (*(const bf16x8*)(p))

__global__ __launch_bounds__(256) void gemm_kernel(
    const ushort_t* __restrict__ xf, const ushort_t* __restrict__ kf,
    float* __restrict__ yre, float* __restrict__ yim, int KB, int acc)
{
    const int cs = blockIdx.x, nb = blockIdx.y;
    const int w = threadIdx.x >> 6, lane = threadIdx.x & 63;
    const int nt = nb * 4 + w;
    const size_t PS = (size_t)NCS * 512;

    f32x16 cre0, cim0, cre1, cim1;
#pragma unroll
    for (int q = 0; q < 16; ++q) { cre0[q] = 0.f; cim0[q] = 0.f; cre1[q] = 0.f; cim1[q] = 0.f; }

    const ushort_t* ab = xf + (size_t)cs * 512 + (size_t)lane * 8;
    const ushort_t* bb = kf + (size_t)cs * 512 + (size_t)(nt * 2) * PS + (size_t)lane * 8;

    const ushort_t* ap = ab;                 // planes kb*8 + {0..7}
    const ushort_t* bp = bb;                 // planes kb*32 + nt*2 + {0,1}
    bf16x8 Brh = LDB(bp), Bih = LDB(bp + PS);
    bf16x8 Arh0 = LDB(ap), Arl0 = LDB(ap + PS), Aih0 = LDB(ap + 2 * PS), Ail0 = LDB(ap + 3 * PS);
    bf16x8 Arh1 = LDB(ap + 4 * PS), Arl1 = LDB(ap + 5 * PS), Aih1 = LDB(ap + 6 * PS), Ail1 = LDB(ap + 7 * PS);

    for (int kb = 0; kb < KB; ++kb) {
        const int kn = (kb + 1 < KB) ? kb + 1 : kb;
        const ushort_t* an = ab + (size_t)kn * 8 * PS;
        const ushort_t* bn = bb + (size_t)kn * 32 * PS;
        const bf16x8 nBrh = LDB(bn), nBih = LDB(bn + PS);
        const bf16x8 nArh0 = LDB(an), nArl0 = LDB(an + PS), nAih0 = LDB(an + 2 * PS), nAil0 = LDB(an + 3 * PS);
        const bf16x8 nArh1 = LDB(an + 4 * PS), nArl1 = LDB(an + 5 * PS), nAih1 = LDB(an + 6 * PS), nAil1 = LDB(an + 7 * PS);

        const bf16x8 NAih0 = bneg(Aih0), NAil0 = bneg(Ail0);
        const bf16x8 NAih1 = bneg(Aih1), NAil1 = bneg(Ail1);

        MFMA(cre0, Arh0, Brh); MFMA(cre0, Arl0, Brh);
        MFMA(cre0, NAih0, Bih); MFMA(cre0, NAil0, Bih);
        MFMA(cim0, Arh0, Bih); MFMA(cim0, Arl0, Bih);
        MFMA(cim0, Aih0, Brh); MFMA(cim0, Ail0, Brh);
        MFMA(cre1, Arh1, Brh); MFMA(cre1, Arl1, Brh);
        MFMA(cre1, NAih1, Bih); MFMA(cre1, NAil1, Bih);
        MFMA(cim1, Arh1, Bih); MFMA(cim1, Arl1, Bih);
        MFMA(cim1, Aih1, Brh); MFMA(cim1, Ail1, Brh);

        Brh = nBrh; Bih = nBih;
        Arh0 = nArh0; Arl0 = nArl0; Aih0 = nAih0; Ail0 = nAil0;
        Arh1 = nArh1; Arl1 = nArl1; Aih1 = nAih1; Ail1 = nAil1;
    }

    // C/D layout: col=lane&31, row=(reg&3)+8*(reg>>2)+4*(lane>>5)
    const int col = lane & 31, rhi = (lane >> 5) * 4;
    const int n = nb * 128 + w * 32 + col;
#pragma unroll
    for (int mt = 0; mt < 2; ++mt) {
        const f32x16 cr = mt ? cre1 : cre0;
        const f32x16 ci = mt ? cim1 : cim0;
#pragma unroll
        for (int reg = 0; reg < 16; ++reg) {
            const int row = (reg & 3) + 8 * (reg >> 2) + rhi;
            const size_t off = ((size_t)cs * B + mt * 32 + row) * 512 + n;
            float vr = cr[reg], vi = ci[reg];
            if (acc) { vr += yre[off]; vi += yim[off]; }
            yre[off] = vr; yim[off] = vi;
        }
    }
}

// ---------------------------------------------------------------------------
// ifft: mirror half-spectrum (cs = ky*9+kx), 2D inverse FFT, +bias.
// ---------------------------------------------------------------------------
__global__ __launch_bounds__(256, 4) void ifft_y_kernel(
    const float* __restrict__ yre, const float* __restrict__ yim,
    const float* __restrict__ bias, float* __restrict__ out)
{
    __shared__ float yr_s[NCS][17], yi_s[NCS][17];
    __shared__ float t_re[16][271], t_im[16][271];
    __shared__ float ost[2][256][9];
    const int tid = threadIdx.x;
    const int ng = blockIdx.x;   // 0..31
    const int b = blockIdx.y;
    const int n0 = ng * 16;
    for (int t = tid; t < NCS * 16; t += 256) {
        const int cs = t >> 4, nl = t & 15;
        const size_t off = ((size_t)cs * B + b) * 512 + n0 + nl;
        yr_s[cs][nl] = yre[off];
        yi_s[cs][nl] = yim[off];
    }
    __syncthreads();

    const int g = tid >> 4, l = tid & 15;

    // pass 1: row ky=l, Hermitian mirror, inverse FFT-16 over kx
    float Yr[16], Yi[16];
#pragma unroll
    for (int kx = 0; kx < 16; ++kx) {
        if (kx <= 8) {
            const int cs = l * 9 + kx;
            Yr[kx] = yr_s[cs][g]; Yi[kx] = yi_s[cs][g];
        } else {
            const int cs = ((16 - l) & 15) * 9 + (16 - kx);
            Yr[kx] = yr_s[cs][g]; Yi[kx] = -yi_s[cs][g];
        }
    }
    fft16<true>(Yr, Yi);
#pragma unroll
    for (int sx = 0; sx < 16; ++sx) {
        t_re[g][sx * 17 + l] = Yr[DR4[sx]];
        t_im[g][sx * 17 + l] = Yi[DR4[sx]];
    }
    __syncthreads();

    // pass 2: column sx=l, inverse FFT-16 over ky, real part only
    float Tr[16], Ti[16];
#pragma unroll
    for (int n = 0; n < 16; ++n) { Tr[n] = t_re[g][l * 17 + n]; Ti[n] = t_im[g][l * 17 + n]; }
    fft16<true>(Tr, Ti);
    const int fl = g >> 3, pq = g & 7;
#pragma unroll
    for (int sy = 0; sy < 16; ++sy)
        ost[fl][sy * 16 + l][pq] = Tr[DR4[sy]] * (1.f / 256.f);
    __syncthreads();

    const int f0 = ng * 2;
    for (int t = tid; t < 4096; t += 256) {
        const int flv = t >> 11, e = t & 2047;
        out[((size_t)b * F + f0 + flv) * NS + e] = ost[flv][e >> 3][e & 7] + bias[f0 + flv];
    }
}

// ---------------------------------------------------------------------------
extern "C" void kernel_launch(void* const* d_in, const int* in_sizes, int n_in,
                              void* d_out, int out_size, void* d_ws, size_t ws_size,
                              hipStream_t stream)
{
    const float* x = (const float*)d_in[0];
    const float* kern = (const float*)d_in[1];
    const float* bias = (const float*)d_in[2];
    const int* pt = (const int*)d_in[3];
    float* out = (float*)d_out;

    // largest in-feature chunk CI that fits workspace
    int CI = 2;
    const int cands[6] = {64, 32, 16, 8, 4, 2};
    for (int t = 0; t < 6; ++t) {
        const int KBc = cands[t] / 2;
        const size_t need = 65536                          // pt2
                          + (size_t)NCS * KBc * 8192       // xf (4 planes bf16)
                          + (size_t)NCS * KBc * 32768      // kf (2 planes bf16)
                          + 2 * (size_t)NCS * B * 512 * 4; // yf re/im fp32
        if (need <= ws_size) { CI = cands[t]; break; }
    }
    const int KB = CI / 2;

    char* p = (char*)d_ws;
    int* pt2 = (int*)p;          p += 65536;
    ushort_t* xf = (ushort_t*)p; p += (size_t)NCS * KB * 8192;
    ushort_t* kf = (ushort_t*)p; p += (size_t)NCS * KB * 32768;
    float* yre = (float*)p;      p += (size_t)NCS * B * 512 * 4;
    float* yim = (float*)p;

    permute_pt_kernel<<<64, 256, 0, stream>>>(pt, pt2);

    const int nch = IFT / CI;
    for (int ch = 0; ch < nch; ++ch) {
        const int i0 = ch * CI;
        fft_x_kernel<<<dim3(32, CI), 256, 0, stream>>>(x, xf, i0, KB);
        fft_k_kernel<<<dim3(64, CI), 256, 0, stream>>>(kern, pt2, kf, i0, KB);
        gemm_kernel<<<dim3(NCS, 4), 256, 0, stream>>>(xf, kf, yre, yim, KB, ch > 0);
    }
    ifft_y_kernel<<<dim3(32, B), 256, 0, stream>>>(yre, yim, bias, out);
}